// Round 1
// baseline (3186.096 us; speedup 1.0000x reference)
//
#include <hip/hip_runtime.h>
#include <math.h>

#define N_NODES 50000
#define N_EDGES 800000
#define D 256

// ---------------- edge-degree count ----------------
__global__ void k_count(const int* __restrict__ dst, float* __restrict__ cnt) {
    int e = blockIdx.x * blockDim.x + threadIdx.x;
    if (e < N_EDGES) atomicAdd(&cnt[dst[e]], 1.0f);
}

// ---------------- layer-1 scatter: agg1[dst] += x[src] (wave per edge) ----------------
__global__ __launch_bounds__(256) void k_scatter1(const int* __restrict__ src,
                                                  const int* __restrict__ dst,
                                                  const float* __restrict__ x,
                                                  float* __restrict__ agg) {
    int e = blockIdx.x * 4 + (threadIdx.x >> 6);
    int lane = threadIdx.x & 63;
    if (e >= N_EDGES) return;
    int s = src[e], d = dst[e];
    const float4 val = *(const float4*)(x + (size_t)s * D + lane * 4);
    float* o = agg + (size_t)d * D + lane * 4;
    atomicAdd(o + 0, val.x);
    atomicAdd(o + 1, val.y);
    atomicAdd(o + 2, val.z);
    atomicAdd(o + 3, val.w);
}

// ---------------- normalize agg -> mean in place ----------------
__global__ void k_norm(float* __restrict__ agg, const float* __restrict__ cnt) {
    size_t i = (size_t)blockIdx.x * blockDim.x + threadIdx.x;  // float4 index
    if (i >= (size_t)N_NODES * (D / 4)) return;
    int row = (int)(i / (D / 4));
    float inv = 1.0f / fmaxf(cnt[row], 1.0f);
    float4* p = (float4*)agg + i;
    float4 v = *p;
    v.x *= inv; v.y *= inv; v.z *= inv; v.w *= inv;
    *p = v;
}

// ---------------- fused layer-1 GEMM: h1 = relu([mean;x] @ [Wl;Wr]^T + b) ----------------
#define TM 64
#define TN 64
#define TK 32
#define LDT (TM + 4)  // 68 floats: 16B-aligned rows, conflict-breaking pad

__global__ __launch_bounds__(256)
void k_gemm1(const float* __restrict__ Am,   // mean1 [N,256]
             const float* __restrict__ Ax,   // x     [N,256]
             const float* __restrict__ Wl,   // [256,256]
             const float* __restrict__ Wr,   // [256,256]
             const float* __restrict__ bias, // [256]
             float* __restrict__ out) {      // h1 [N,256]
    __shared__ __align__(16) float As[TK][LDT];
    __shared__ __align__(16) float Bs[TK][LDT];
    int tid = threadIdx.x;
    int brow = blockIdx.x;
    int bcol = blockIdx.y;
    int tx = tid & 15, ty = tid >> 4;
    float acc[4][4] = {};

    for (int kt = 0; kt < 512; kt += TK) {
        #pragma unroll
        for (int i = 0; i < 2; i++) {
            int f = 2 * tid + i;
            int r = f >> 3;           // 0..63
            int kc = (f & 7) * 4;     // 0,4,..,28
            int gk = kt + kc;
            // A tile (rows of [mean ; x])
            int gr = brow * TM + r;
            float4 va = make_float4(0.f, 0.f, 0.f, 0.f);
            if (gr < N_NODES) {
                const float* Ap = (gk < 256) ? (Am + (size_t)gr * 256 + gk)
                                             : (Ax + (size_t)gr * 256 + (gk - 256));
                va = *(const float4*)Ap;
            }
            As[kc + 0][r] = va.x; As[kc + 1][r] = va.y;
            As[kc + 2][r] = va.z; As[kc + 3][r] = va.w;
            // B tile (rows of [Wl ; Wr])
            int gc = bcol * TN + r;
            const float* Bp = (gk < 256) ? (Wl + (size_t)gc * 256 + gk)
                                         : (Wr + (size_t)gc * 256 + (gk - 256));
            float4 vb = *(const float4*)Bp;
            Bs[kc + 0][r] = vb.x; Bs[kc + 1][r] = vb.y;
            Bs[kc + 2][r] = vb.z; Bs[kc + 3][r] = vb.w;
        }
        __syncthreads();
        #pragma unroll
        for (int k = 0; k < TK; k++) {
            float4 a = *(const float4*)&As[k][ty * 4];
            float4 b = *(const float4*)&Bs[k][tx * 4];
            float av[4] = {a.x, a.y, a.z, a.w};
            float bv[4] = {b.x, b.y, b.z, b.w};
            #pragma unroll
            for (int i = 0; i < 4; i++)
                #pragma unroll
                for (int j = 0; j < 4; j++)
                    acc[i][j] += av[i] * bv[j];
        }
        __syncthreads();
    }
    int gc0 = bcol * TN + tx * 4;
    #pragma unroll
    for (int i = 0; i < 4; i++) {
        int gr = brow * TM + ty * 4 + i;
        if (gr >= N_NODES) continue;
        float4 o;
        o.x = fmaxf(acc[i][0] + bias[gc0 + 0], 0.f);
        o.y = fmaxf(acc[i][1] + bias[gc0 + 1], 0.f);
        o.z = fmaxf(acc[i][2] + bias[gc0 + 2], 0.f);
        o.w = fmaxf(acc[i][3] + bias[gc0 + 3], 0.f);
        *(float4*)(out + (size_t)gr * 256 + gc0) = o;
    }
}

// ---------------- mention-row aggregation: aggm += h1[src] where dst==m ----------------
__global__ __launch_bounds__(256) void k_aggm(const int* __restrict__ src,
                                              const int* __restrict__ dst,
                                              const int* __restrict__ mention,
                                              const float* __restrict__ h1,
                                              float* __restrict__ aggm) {
    int e = blockIdx.x * 4 + (threadIdx.x >> 6);
    int lane = threadIdx.x & 63;
    if (e >= N_EDGES) return;
    if (dst[e] != mention[0]) return;
    const float4 val = *(const float4*)(h1 + (size_t)src[e] * D + lane * 4);
    float* o = aggm + lane * 4;
    atomicAdd(o + 0, val.x);
    atomicAdd(o + 1, val.y);
    atomicAdd(o + 2, val.z);
    atomicAdd(o + 3, val.w);
}

// ---------------- v = h2[mention] (one row); c = b2 . v ----------------
__global__ __launch_bounds__(256) void k_v(const int* __restrict__ mention,
                                           const float* __restrict__ cnt,
                                           const float* __restrict__ aggm,
                                           const float* __restrict__ h1,
                                           const float* __restrict__ W2l,
                                           const float* __restrict__ W2r,
                                           const float* __restrict__ b2,
                                           float* __restrict__ v,
                                           float* __restrict__ cout) {
    __shared__ float sm[D], sh[D], red[256];
    int m = mention[0];
    int t = threadIdx.x;
    float inv = 1.0f / fmaxf(cnt[m], 1.0f);
    sm[t] = aggm[t] * inv;
    sh[t] = h1[(size_t)m * D + t];
    __syncthreads();
    float acc = b2[t];
    for (int k = 0; k < D; k++)
        acc += sm[k] * W2l[(size_t)t * D + k] + sh[k] * W2r[(size_t)t * D + k];
    v[t] = acc;
    red[t] = b2[t] * acc;
    __syncthreads();
    for (int o = 128; o; o >>= 1) {
        if (t < o) red[t] += red[t + o];
        __syncthreads();
    }
    if (t == 0) cout[0] = red[0];
}

// ---------------- u1 = W2l^T v, u2 = W2r^T v ----------------
__global__ __launch_bounds__(256) void k_u(const float* __restrict__ W2l,
                                           const float* __restrict__ W2r,
                                           const float* __restrict__ v,
                                           float* __restrict__ u) {
    __shared__ float sv[D];
    int k = threadIdx.x;
    sv[k] = v[k];
    __syncthreads();
    float a1 = 0.f, a2 = 0.f;
    for (int n = 0; n < D; n++) {
        a1 += W2l[(size_t)n * D + k] * sv[n];
        a2 += W2r[(size_t)n * D + k] * sv[n];
    }
    u[k] = a1;
    u[D + k] = a2;
}

// ---------------- s[j] = h1[j].u1 ; t[j] = h1[j].u2 (wave per node) ----------------
__global__ __launch_bounds__(256) void k_st(const float* __restrict__ h1,
                                            const float* __restrict__ u,
                                            float* __restrict__ s,
                                            float* __restrict__ t_) {
    int node = blockIdx.x * 4 + (threadIdx.x >> 6);
    int lane = threadIdx.x & 63;
    if (node >= N_NODES) return;
    const float4 hv = *(const float4*)(h1 + (size_t)node * D + lane * 4);
    const float4 u1 = *(const float4*)(u + lane * 4);
    const float4 u2 = *(const float4*)(u + D + lane * 4);
    float ps = hv.x * u1.x + hv.y * u1.y + hv.z * u1.z + hv.w * u1.w;
    float pt = hv.x * u2.x + hv.y * u2.y + hv.z * u2.z + hv.w * u2.w;
    #pragma unroll
    for (int off = 32; off; off >>= 1) {
        ps += __shfl_down(ps, off);
        pt += __shfl_down(pt, off);
    }
    if (lane == 0) { s[node] = ps; t_[node] = pt; }
}

// ---------------- scalar edge scatter: aggS[dst] += s[src] ----------------
__global__ void k_scatterS(const int* __restrict__ src, const int* __restrict__ dst,
                           const float* __restrict__ s, float* __restrict__ aggS) {
    int e = blockIdx.x * blockDim.x + threadIdx.x;
    if (e < N_EDGES) atomicAdd(&aggS[dst[e]], s[src[e]]);
}

// ---------------- logits ----------------
__global__ void k_logits(const float* __restrict__ aggS, const float* __restrict__ cnt,
                         const float* __restrict__ t_, const float* __restrict__ cptr,
                         float* __restrict__ logits) {
    int i = blockIdx.x * blockDim.x + threadIdx.x;
    if (i < N_NODES)
        logits[i] = aggS[i] / fmaxf(cnt[i], 1.0f) + t_[i] + cptr[0];
}

// ---------------- softmax over N (single block) ----------------
__global__ __launch_bounds__(1024) void k_softmax(const float* __restrict__ logits,
                                                  float* __restrict__ out) {
    __shared__ float red[1024];
    int t = threadIdx.x;
    float mx = -INFINITY;
    for (int i = t; i < N_NODES; i += 1024) mx = fmaxf(mx, logits[i]);
    red[t] = mx;
    __syncthreads();
    for (int o = 512; o; o >>= 1) {
        if (t < o) red[t] = fmaxf(red[t], red[t + o]);
        __syncthreads();
    }
    float gmax = red[0];
    __syncthreads();
    float sm = 0.f;
    for (int i = t; i < N_NODES; i += 1024) sm += __expf(logits[i] - gmax);
    red[t] = sm;
    __syncthreads();
    for (int o = 512; o; o >>= 1) {
        if (t < o) red[t] += red[t + o];
        __syncthreads();
    }
    float inv = 1.0f / red[0];
    for (int i = t; i < N_NODES; i += 1024) out[i] = __expf(logits[i] - gmax) * inv;
}

extern "C" void kernel_launch(void* const* d_in, const int* in_sizes, int n_in,
                              void* d_out, int out_size, void* d_ws, size_t ws_size,
                              hipStream_t stream) {
    const float* x   = (const float*)d_in[0];
    const int*   ei  = (const int*)d_in[1];
    const int*   src = ei;
    const int*   dst = ei + N_EDGES;
    const int*   mention = (const int*)d_in[2];
    const float* W1l = (const float*)d_in[3];
    const float* b1  = (const float*)d_in[4];
    const float* W1r = (const float*)d_in[5];
    const float* W2l = (const float*)d_in[6];
    const float* b2  = (const float*)d_in[7];
    const float* W2r = (const float*)d_in[8];

    float* ws    = (float*)d_ws;
    float* agg   = ws;                            // N*D (zeroed; becomes mean1)
    float* cnt   = agg + (size_t)N_NODES * D;     // N   (zeroed)
    float* aggS  = cnt + N_NODES;                 // N   (zeroed)
    float* aggm  = aggS + N_NODES;                // D   (zeroed)
    float* h1    = aggm + D;                      // N*D
    float* s     = h1 + (size_t)N_NODES * D;      // N
    float* t_    = s + N_NODES;                   // N
    float* logit = t_ + N_NODES;                  // N
    float* v     = logit + N_NODES;               // D
    float* u     = v + D;                         // 2*D
    float* c     = u + 2 * D;                     // 1

    size_t zeroFloats = (size_t)N_NODES * D + N_NODES + N_NODES + D;
    hipMemsetAsync(agg, 0, zeroFloats * sizeof(float), stream);

    k_count<<<(N_EDGES + 255) / 256, 256, 0, stream>>>(dst, cnt);
    k_scatter1<<<N_EDGES / 4, 256, 0, stream>>>(src, dst, x, agg);
    k_norm<<<(N_NODES * (D / 4) + 255) / 256, 256, 0, stream>>>(agg, cnt);

    dim3 g1((N_NODES + TM - 1) / TM, 256 / TN);
    k_gemm1<<<g1, 256, 0, stream>>>(agg, x, W1l, W1r, b1, h1);

    k_aggm<<<N_EDGES / 4, 256, 0, stream>>>(src, dst, mention, h1, aggm);
    k_v<<<1, 256, 0, stream>>>(mention, cnt, aggm, h1, W2l, W2r, b2, v, c);
    k_u<<<1, 256, 0, stream>>>(W2l, W2r, v, u);
    k_st<<<N_NODES / 4, 256, 0, stream>>>(h1, u, s, t_);
    k_scatterS<<<(N_EDGES + 255) / 256, 256, 0, stream>>>(src, dst, s, aggS);
    k_logits<<<(N_NODES + 255) / 256, 256, 0, stream>>>(aggS, cnt, t_, c, logit);
    k_softmax<<<1, 1024, 0, stream>>>(logit, (float*)d_out);
}

// Round 2
// 640.897 us; speedup vs baseline: 4.9713x; 4.9713x over previous
//
#include <hip/hip_runtime.h>
#include <math.h>

#define N_NODES 50000
#define N_EDGES 800000
#define D 256

// ---------------- edge-degree count (int atomics) ----------------
__global__ void k_count(const int* __restrict__ dst, int* __restrict__ deg) {
    int e = blockIdx.x * blockDim.x + threadIdx.x;
    if (e < N_EDGES) atomicAdd(&deg[dst[e]], 1);
}

// ---------------- exclusive prefix sum of deg -> cursor (row starts) ----------------
__global__ __launch_bounds__(1024) void k_scan(const int* __restrict__ deg,
                                               int* __restrict__ cursor) {
    __shared__ int sums[1024];
    const int CH = (N_NODES + 1023) / 1024;  // 49
    int t = threadIdx.x;
    int base = t * CH;
    int lim = min(base + CH, N_NODES);
    int sum = 0;
    for (int i = base; i < lim; i++) sum += deg[i];
    sums[t] = sum;
    __syncthreads();
    for (int o = 1; o < 1024; o <<= 1) {
        int val = (t >= o) ? sums[t - o] : 0;
        __syncthreads();
        sums[t] += val;
        __syncthreads();
    }
    int excl = (t == 0) ? 0 : sums[t - 1];
    for (int i = base; i < lim; i++) { cursor[i] = excl; excl += deg[i]; }
}

// ---------------- bucket edges by dst: csr_src[pos] = src ----------------
// After this kernel, cursor[i] == rowstart[i] + deg[i] (row END); start = cursor[i]-deg[i].
__global__ void k_bucket(const int* __restrict__ src, const int* __restrict__ dst,
                         int* __restrict__ cursor, int* __restrict__ csr_src) {
    int e = blockIdx.x * blockDim.x + threadIdx.x;
    if (e >= N_EDGES) return;
    int pos = atomicAdd(&cursor[dst[e]], 1);
    csr_src[pos] = src[e];
}

// ---------------- per-node mean aggregation (wave per node, CSR gather) ----------------
__global__ __launch_bounds__(256) void k_agg(const int* __restrict__ cursor,
                                             const int* __restrict__ deg,
                                             const int* __restrict__ csr_src,
                                             const float* __restrict__ x,
                                             float* __restrict__ mean) {
    int node = blockIdx.x * 4 + (threadIdx.x >> 6);
    int lane = threadIdx.x & 63;
    if (node >= N_NODES) return;
    int d = deg[node];
    int end = cursor[node];   // row end after bucketing
    int start = end - d;
    float4 acc0 = make_float4(0.f, 0.f, 0.f, 0.f);
    float4 acc1 = make_float4(0.f, 0.f, 0.f, 0.f);
    int j = start;
    for (; j + 2 <= end; j += 2) {
        int s0 = csr_src[j];       // wave-uniform -> scalar load
        int s1 = csr_src[j + 1];
        float4 v0 = *(const float4*)(x + (size_t)s0 * D + lane * 4);
        float4 v1 = *(const float4*)(x + (size_t)s1 * D + lane * 4);
        acc0.x += v0.x; acc0.y += v0.y; acc0.z += v0.z; acc0.w += v0.w;
        acc1.x += v1.x; acc1.y += v1.y; acc1.z += v1.z; acc1.w += v1.w;
    }
    if (j < end) {
        int s0 = csr_src[j];
        float4 v0 = *(const float4*)(x + (size_t)s0 * D + lane * 4);
        acc0.x += v0.x; acc0.y += v0.y; acc0.z += v0.z; acc0.w += v0.w;
    }
    float inv = 1.0f / fmaxf((float)d, 1.0f);
    float4 o;
    o.x = (acc0.x + acc1.x) * inv;
    o.y = (acc0.y + acc1.y) * inv;
    o.z = (acc0.z + acc1.z) * inv;
    o.w = (acc0.w + acc1.w) * inv;
    *(float4*)(mean + (size_t)node * D + lane * 4) = o;
}

// ---------------- fused layer-1 GEMM: h1 = relu([mean;x] @ [Wl;Wr]^T + b) ----------------
#define TM 64
#define TN 64
#define TK 32
#define LDT (TM + 4)

__global__ __launch_bounds__(256)
void k_gemm1(const float* __restrict__ Am,   // mean1 [N,256]
             const float* __restrict__ Ax,   // x     [N,256]
             const float* __restrict__ Wl,   // [256,256]
             const float* __restrict__ Wr,   // [256,256]
             const float* __restrict__ bias, // [256]
             float* __restrict__ out) {      // h1 [N,256]
    __shared__ __align__(16) float As[TK][LDT];
    __shared__ __align__(16) float Bs[TK][LDT];
    int tid = threadIdx.x;
    int brow = blockIdx.x;
    int bcol = blockIdx.y;
    int tx = tid & 15, ty = tid >> 4;
    float acc[4][4] = {};

    for (int kt = 0; kt < 512; kt += TK) {
        #pragma unroll
        for (int i = 0; i < 2; i++) {
            int f = 2 * tid + i;
            int r = f >> 3;
            int kc = (f & 7) * 4;
            int gk = kt + kc;
            int gr = brow * TM + r;
            float4 va = make_float4(0.f, 0.f, 0.f, 0.f);
            if (gr < N_NODES) {
                const float* Ap = (gk < 256) ? (Am + (size_t)gr * 256 + gk)
                                             : (Ax + (size_t)gr * 256 + (gk - 256));
                va = *(const float4*)Ap;
            }
            As[kc + 0][r] = va.x; As[kc + 1][r] = va.y;
            As[kc + 2][r] = va.z; As[kc + 3][r] = va.w;
            int gc = bcol * TN + r;
            const float* Bp = (gk < 256) ? (Wl + (size_t)gc * 256 + gk)
                                         : (Wr + (size_t)gc * 256 + (gk - 256));
            float4 vb = *(const float4*)Bp;
            Bs[kc + 0][r] = vb.x; Bs[kc + 1][r] = vb.y;
            Bs[kc + 2][r] = vb.z; Bs[kc + 3][r] = vb.w;
        }
        __syncthreads();
        #pragma unroll
        for (int k = 0; k < TK; k++) {
            float4 a = *(const float4*)&As[k][ty * 4];
            float4 b = *(const float4*)&Bs[k][tx * 4];
            float av[4] = {a.x, a.y, a.z, a.w};
            float bv[4] = {b.x, b.y, b.z, b.w};
            #pragma unroll
            for (int i = 0; i < 4; i++)
                #pragma unroll
                for (int j = 0; j < 4; j++)
                    acc[i][j] += av[i] * bv[j];
        }
        __syncthreads();
    }
    int gc0 = bcol * TN + tx * 4;
    #pragma unroll
    for (int i = 0; i < 4; i++) {
        int gr = brow * TM + ty * 4 + i;
        if (gr >= N_NODES) continue;
        float4 o;
        o.x = fmaxf(acc[i][0] + bias[gc0 + 0], 0.f);
        o.y = fmaxf(acc[i][1] + bias[gc0 + 1], 0.f);
        o.z = fmaxf(acc[i][2] + bias[gc0 + 2], 0.f);
        o.w = fmaxf(acc[i][3] + bias[gc0 + 3], 0.f);
        *(float4*)(out + (size_t)gr * 256 + gc0) = o;
    }
}

// ---------------- v = h2[mention]; c = b2 . v (mention row via CSR) ----------------
__global__ __launch_bounds__(256) void k_v(const int* __restrict__ mention,
                                           const int* __restrict__ deg,
                                           const int* __restrict__ cursor,
                                           const int* __restrict__ csr_src,
                                           const float* __restrict__ h1,
                                           const float* __restrict__ W2l,
                                           const float* __restrict__ W2r,
                                           const float* __restrict__ b2,
                                           float* __restrict__ v,
                                           float* __restrict__ cout) {
    __shared__ float sm[D], sh[D], red[256];
    int m = mention[0];
    int t = threadIdx.x;
    int dm = deg[m];
    int end = cursor[m];
    int start = end - dm;
    float a = 0.f;
    for (int j = start; j < end; j++)
        a += h1[(size_t)csr_src[j] * D + t];   // coalesced across t
    sm[t] = a / fmaxf((float)dm, 1.0f);
    sh[t] = h1[(size_t)m * D + t];
    __syncthreads();
    float acc = b2[t];
    for (int k = 0; k < D; k++)
        acc += sm[k] * W2l[(size_t)t * D + k] + sh[k] * W2r[(size_t)t * D + k];
    v[t] = acc;
    red[t] = b2[t] * acc;
    __syncthreads();
    for (int o = 128; o; o >>= 1) {
        if (t < o) red[t] += red[t + o];
        __syncthreads();
    }
    if (t == 0) cout[0] = red[0];
}

// ---------------- u1 = W2l^T v, u2 = W2r^T v ----------------
__global__ __launch_bounds__(256) void k_u(const float* __restrict__ W2l,
                                           const float* __restrict__ W2r,
                                           const float* __restrict__ v,
                                           float* __restrict__ u) {
    __shared__ float sv[D];
    int k = threadIdx.x;
    sv[k] = v[k];
    __syncthreads();
    float a1 = 0.f, a2 = 0.f;
    for (int n = 0; n < D; n++) {
        a1 += W2l[(size_t)n * D + k] * sv[n];
        a2 += W2r[(size_t)n * D + k] * sv[n];
    }
    u[k] = a1;
    u[D + k] = a2;
}

// ---------------- s[j] = h1[j].u1 ; t[j] = h1[j].u2 (wave per node) ----------------
__global__ __launch_bounds__(256) void k_st(const float* __restrict__ h1,
                                            const float* __restrict__ u,
                                            float* __restrict__ s,
                                            float* __restrict__ t_) {
    int node = blockIdx.x * 4 + (threadIdx.x >> 6);
    int lane = threadIdx.x & 63;
    if (node >= N_NODES) return;
    const float4 hv = *(const float4*)(h1 + (size_t)node * D + lane * 4);
    const float4 u1 = *(const float4*)(u + lane * 4);
    const float4 u2 = *(const float4*)(u + D + lane * 4);
    float ps = hv.x * u1.x + hv.y * u1.y + hv.z * u1.z + hv.w * u1.w;
    float pt = hv.x * u2.x + hv.y * u2.y + hv.z * u2.z + hv.w * u2.w;
    #pragma unroll
    for (int off = 32; off; off >>= 1) {
        ps += __shfl_down(ps, off);
        pt += __shfl_down(pt, off);
    }
    if (lane == 0) { s[node] = ps; t_[node] = pt; }
}

// ---------------- logits: gather s over CSR row + t + c ----------------
__global__ void k_logits(const int* __restrict__ deg, const int* __restrict__ cursor,
                         const int* __restrict__ csr_src,
                         const float* __restrict__ s, const float* __restrict__ t_,
                         const float* __restrict__ cptr, float* __restrict__ logits) {
    int i = blockIdx.x * blockDim.x + threadIdx.x;
    if (i >= N_NODES) return;
    int d = deg[i];
    int end = cursor[i];
    int start = end - d;
    float sum = 0.f;
    for (int j = start; j < end; j++) sum += s[csr_src[j]];
    logits[i] = sum / fmaxf((float)d, 1.0f) + t_[i] + cptr[0];
}

// ---------------- softmax over N (single block) ----------------
__global__ __launch_bounds__(1024) void k_softmax(const float* __restrict__ logits,
                                                  float* __restrict__ out) {
    __shared__ float red[1024];
    int t = threadIdx.x;
    float mx = -INFINITY;
    for (int i = t; i < N_NODES; i += 1024) mx = fmaxf(mx, logits[i]);
    red[t] = mx;
    __syncthreads();
    for (int o = 512; o; o >>= 1) {
        if (t < o) red[t] = fmaxf(red[t], red[t + o]);
        __syncthreads();
    }
    float gmax = red[0];
    __syncthreads();
    float sm = 0.f;
    for (int i = t; i < N_NODES; i += 1024) sm += __expf(logits[i] - gmax);
    red[t] = sm;
    __syncthreads();
    for (int o = 512; o; o >>= 1) {
        if (t < o) red[t] += red[t + o];
        __syncthreads();
    }
    float inv = 1.0f / red[0];
    for (int i = t; i < N_NODES; i += 1024) out[i] = __expf(logits[i] - gmax) * inv;
}

extern "C" void kernel_launch(void* const* d_in, const int* in_sizes, int n_in,
                              void* d_out, int out_size, void* d_ws, size_t ws_size,
                              hipStream_t stream) {
    const float* x   = (const float*)d_in[0];
    const int*   ei  = (const int*)d_in[1];
    const int*   src = ei;
    const int*   dst = ei + N_EDGES;
    const int*   mention = (const int*)d_in[2];
    const float* W1l = (const float*)d_in[3];
    const float* b1  = (const float*)d_in[4];
    const float* W1r = (const float*)d_in[5];
    const float* W2l = (const float*)d_in[6];
    const float* b2  = (const float*)d_in[7];
    const float* W2r = (const float*)d_in[8];

    float* ws     = (float*)d_ws;
    float* mean   = ws;                              // N*D
    float* h1     = mean + (size_t)N_NODES * D;      // N*D
    float* s      = h1 + (size_t)N_NODES * D;        // N
    float* t_     = s + N_NODES;                     // N
    float* logit  = t_ + N_NODES;                    // N
    float* v      = logit + N_NODES;                 // D
    float* u      = v + D;                           // 2*D
    float* c      = u + 2 * D;                       // 1
    int*   deg    = (int*)(c + 1);                   // N (zeroed)
    int*   cursor = deg + N_NODES;                   // N
    int*   csr    = cursor + N_NODES;                // E

    hipMemsetAsync(deg, 0, N_NODES * sizeof(int), stream);

    k_count <<<(N_EDGES + 255) / 256, 256, 0, stream>>>(dst, deg);
    k_scan  <<<1, 1024, 0, stream>>>(deg, cursor);
    k_bucket<<<(N_EDGES + 255) / 256, 256, 0, stream>>>(src, dst, cursor, csr);
    k_agg   <<<(N_NODES + 3) / 4, 256, 0, stream>>>(cursor, deg, csr, x, mean);

    dim3 g1((N_NODES + TM - 1) / TM, 256 / TN);
    k_gemm1<<<g1, 256, 0, stream>>>(mean, x, W1l, W1r, b1, h1);

    k_v     <<<1, 256, 0, stream>>>(mention, deg, cursor, csr, h1, W2l, W2r, b2, v, c);
    k_u     <<<1, 256, 0, stream>>>(W2l, W2r, v, u);
    k_st    <<<(N_NODES + 3) / 4, 256, 0, stream>>>(h1, u, s, t_);
    k_logits<<<(N_NODES + 255) / 256, 256, 0, stream>>>(deg, cursor, csr, s, t_, c, logit);
    k_softmax<<<1, 1024, 0, stream>>>(logit, (float*)d_out);
}

// Round 3
// 486.804 us; speedup vs baseline: 6.5449x; 1.3165x over previous
//
#include <hip/hip_runtime.h>
#include <math.h>

#define N_NODES 50000
#define N_EDGES 800000
#define D 256
#define K2 512        // concat [mean | x] feature dim
#define M_PAD 50048   // 391 * 128 rows (GEMM padding)
#define BM 128
#define BN 128
#define BK 32

typedef __attribute__((ext_vector_type(8))) short short8;
typedef __attribute__((ext_vector_type(4))) float floatx4;

__device__ __forceinline__ unsigned short bf16_rn(float f) {
    union { float f; unsigned u; } a; a.f = f;
    unsigned r = a.u + 0x7FFF + ((a.u >> 16) & 1);
    return (unsigned short)(r >> 16);
}
__device__ __forceinline__ float bf16_to_f(unsigned short h) {
    union { unsigned u; float f; } a; a.u = ((unsigned)h) << 16;
    return a.f;
}
__device__ __forceinline__ void load_lds16(const void* g, void* lds) {
    __builtin_amdgcn_global_load_lds((const __attribute__((address_space(1))) void*)g,
                                     (__attribute__((address_space(3))) void*)lds, 16, 0, 0);
}

// ---------------- CSR build ----------------
__global__ void k_count(const int* __restrict__ dst, int* __restrict__ deg) {
    int e = blockIdx.x * blockDim.x + threadIdx.x;
    if (e < N_EDGES) atomicAdd(&deg[dst[e]], 1);
}

__global__ __launch_bounds__(1024) void k_scan(const int* __restrict__ deg,
                                               int* __restrict__ cursor) {
    __shared__ int sums[1024];
    const int CH = (N_NODES + 1023) / 1024;
    int t = threadIdx.x;
    int base = t * CH;
    int lim = min(base + CH, N_NODES);
    int sum = 0;
    for (int i = base; i < lim; i++) sum += deg[i];
    sums[t] = sum;
    __syncthreads();
    for (int o = 1; o < 1024; o <<= 1) {
        int val = (t >= o) ? sums[t - o] : 0;
        __syncthreads();
        sums[t] += val;
        __syncthreads();
    }
    int excl = (t == 0) ? 0 : sums[t - 1];
    for (int i = base; i < lim; i++) { cursor[i] = excl; excl += deg[i]; }
}

// after this, cursor[i] == row END; start = cursor[i]-deg[i]
__global__ void k_bucket(const int* __restrict__ src, const int* __restrict__ dst,
                         int* __restrict__ cursor, int* __restrict__ csr_src) {
    int e = blockIdx.x * blockDim.x + threadIdx.x;
    if (e >= N_EDGES) return;
    int pos = atomicAdd(&cursor[dst[e]], 1);
    csr_src[pos] = src[e];
}

// ---------------- split x into bf16 hi/lo halves of A ----------------
__global__ void k_splitX(const float* __restrict__ x, unsigned short* __restrict__ Ahi,
                         unsigned short* __restrict__ Alo) {
    int t = blockIdx.x * blockDim.x + threadIdx.x;  // over N*64
    if (t >= N_NODES * 64) return;
    int m = t >> 6, j = (t & 63) * 4;
    float4 v = *(const float4*)&x[(size_t)m * D + j];
    ushort4 hi, lo;
    hi.x = bf16_rn(v.x); lo.x = bf16_rn(v.x - bf16_to_f(hi.x));
    hi.y = bf16_rn(v.y); lo.y = bf16_rn(v.y - bf16_to_f(hi.y));
    hi.z = bf16_rn(v.z); lo.z = bf16_rn(v.z - bf16_to_f(hi.z));
    hi.w = bf16_rn(v.w); lo.w = bf16_rn(v.w - bf16_to_f(hi.w));
    *(ushort4*)&Ahi[(size_t)m * K2 + 256 + j] = hi;
    *(ushort4*)&Alo[(size_t)m * K2 + 256 + j] = lo;
}

// ---------------- split [W1l|W1r] into bf16 hi/lo B ----------------
__global__ void k_splitB(const float* __restrict__ Wl, const float* __restrict__ Wr,
                         unsigned short* __restrict__ Bhi, unsigned short* __restrict__ Blo) {
    int t = blockIdx.x * blockDim.x + threadIdx.x;  // over 256*128
    if (t >= 256 * 128) return;
    int n = t >> 7, k = (t & 127) * 4;
    const float* srcp = (k < 256) ? &Wl[(size_t)n * 256 + k] : &Wr[(size_t)n * 256 + k - 256];
    float4 v = *(const float4*)srcp;
    ushort4 hi, lo;
    hi.x = bf16_rn(v.x); lo.x = bf16_rn(v.x - bf16_to_f(hi.x));
    hi.y = bf16_rn(v.y); lo.y = bf16_rn(v.y - bf16_to_f(hi.y));
    hi.z = bf16_rn(v.z); lo.z = bf16_rn(v.z - bf16_to_f(hi.z));
    hi.w = bf16_rn(v.w); lo.w = bf16_rn(v.w - bf16_to_f(hi.w));
    *(ushort4*)&Bhi[(size_t)n * K2 + k] = hi;
    *(ushort4*)&Blo[(size_t)n * K2 + k] = lo;
}

// ---------------- mean aggregation (gathers bf16 xhi, writes mean hi/lo) ----------------
__global__ __launch_bounds__(256) void k_agg(const int* __restrict__ cursor,
                                             const int* __restrict__ deg,
                                             const int* __restrict__ csr,
                                             unsigned short* __restrict__ Ahi,
                                             unsigned short* __restrict__ Alo) {
    int node = blockIdx.x * 4 + (threadIdx.x >> 6);
    int lane = threadIdx.x & 63;
    if (node >= N_NODES) return;
    int d = deg[node], end = cursor[node], start = end - d;
    float a0 = 0, a1 = 0, a2 = 0, a3 = 0, b0 = 0, b1 = 0, b2 = 0, b3 = 0;
    int j = start;
    for (; j + 2 <= end; j += 2) {
        int s0 = csr[j], s1 = csr[j + 1];
        ushort4 v0 = *(const ushort4*)&Ahi[(size_t)s0 * K2 + 256 + lane * 4];
        ushort4 v1 = *(const ushort4*)&Ahi[(size_t)s1 * K2 + 256 + lane * 4];
        a0 += bf16_to_f(v0.x); a1 += bf16_to_f(v0.y); a2 += bf16_to_f(v0.z); a3 += bf16_to_f(v0.w);
        b0 += bf16_to_f(v1.x); b1 += bf16_to_f(v1.y); b2 += bf16_to_f(v1.z); b3 += bf16_to_f(v1.w);
    }
    if (j < end) {
        int s0 = csr[j];
        ushort4 v0 = *(const ushort4*)&Ahi[(size_t)s0 * K2 + 256 + lane * 4];
        a0 += bf16_to_f(v0.x); a1 += bf16_to_f(v0.y); a2 += bf16_to_f(v0.z); a3 += bf16_to_f(v0.w);
    }
    float inv = 1.0f / fmaxf((float)d, 1.0f);
    float m0 = (a0 + b0) * inv, m1 = (a1 + b1) * inv, m2 = (a2 + b2) * inv, m3 = (a3 + b3) * inv;
    ushort4 hi, lo;
    hi.x = bf16_rn(m0); lo.x = bf16_rn(m0 - bf16_to_f(hi.x));
    hi.y = bf16_rn(m1); lo.y = bf16_rn(m1 - bf16_to_f(hi.y));
    hi.z = bf16_rn(m2); lo.z = bf16_rn(m2 - bf16_to_f(hi.z));
    hi.w = bf16_rn(m3); lo.w = bf16_rn(m3 - bf16_to_f(hi.w));
    *(ushort4*)&Ahi[(size_t)node * K2 + lane * 4] = hi;
    *(ushort4*)&Alo[(size_t)node * K2 + lane * 4] = lo;
}

// ---------------- exact fp32 h1 rows for mention + its neighbors ----------------
__global__ __launch_bounds__(256) void k_small(const int* __restrict__ mention,
                                               const int* __restrict__ deg,
                                               const int* __restrict__ cursor,
                                               const int* __restrict__ csr,
                                               const float* __restrict__ x,
                                               const float* __restrict__ W1l,
                                               const float* __restrict__ W1r,
                                               const float* __restrict__ b1,
                                               float* __restrict__ h1m) {
    int m = mention[0];
    int dm = min(deg[m], 255);
    int slot = blockIdx.x;
    if (slot > dm) return;
    int startm = cursor[m] - deg[m];
    int node = (slot == 0) ? m : csr[startm + slot - 1];
    __shared__ float smean[D], sx[D];
    int t = threadIdx.x;
    int d = deg[node], end = cursor[node], start = end - d;
    float a = 0.f;
    for (int j = start; j < end; j++) a += x[(size_t)csr[j] * D + t];
    smean[t] = a / fmaxf((float)d, 1.0f);
    sx[t] = x[(size_t)node * D + t];
    __syncthreads();
    float z = b1[t];
    for (int k = 0; k < D; k++)
        z += smean[k] * W1l[(size_t)t * D + k] + sx[k] * W1r[(size_t)t * D + k];
    h1m[(size_t)slot * D + t] = fmaxf(z, 0.f);
}

// ---------------- v = h2[mention] (fp32 exact); c = b2 . v ----------------
__global__ __launch_bounds__(256) void k_v(const int* __restrict__ mention,
                                           const int* __restrict__ deg,
                                           const float* __restrict__ h1m,
                                           const float* __restrict__ W2l,
                                           const float* __restrict__ W2r,
                                           const float* __restrict__ b2,
                                           float* __restrict__ v,
                                           float* __restrict__ cout) {
    __shared__ float sm[D], sh[D], red[256];
    int m = mention[0];
    int dm = min(deg[m], 255);
    int t = threadIdx.x;
    float a = 0.f;
    for (int j = 1; j <= dm; j++) a += h1m[(size_t)j * D + t];
    sm[t] = a / fmaxf((float)deg[m], 1.0f);
    sh[t] = h1m[t];
    __syncthreads();
    float acc = b2[t];
    for (int k = 0; k < D; k++)
        acc += sm[k] * W2l[(size_t)t * D + k] + sh[k] * W2r[(size_t)t * D + k];
    v[t] = acc;
    red[t] = b2[t] * acc;
    __syncthreads();
    for (int o = 128; o; o >>= 1) {
        if (t < o) red[t] += red[t + o];
        __syncthreads();
    }
    if (t == 0) cout[0] = red[0];
}

// ---------------- u1 = W2l^T v, u2 = W2r^T v ----------------
__global__ __launch_bounds__(256) void k_u(const float* __restrict__ W2l,
                                           const float* __restrict__ W2r,
                                           const float* __restrict__ v,
                                           float* __restrict__ u) {
    __shared__ float sv[D];
    int k = threadIdx.x;
    sv[k] = v[k];
    __syncthreads();
    float a1 = 0.f, a2 = 0.f;
    for (int n = 0; n < D; n++) {
        a1 += W2l[(size_t)n * D + k] * sv[n];
        a2 += W2r[(size_t)n * D + k] * sv[n];
    }
    u[k] = a1;
    u[D + k] = a2;
}

// ---------------- fused split-bf16 MFMA GEMM + relu + projection epilogue ----------------
// C = A @ B^T, A=[M_PAD,512] (hi/lo), B=[256,512] (hi/lo); epilogue emits
// s_partial[row] = sum_col relu(C+bias)*u1[col], t_partial likewise.
__global__ __launch_bounds__(256, 2)
void k_gemm_fused(const unsigned short* __restrict__ Ahi,
                  const unsigned short* __restrict__ Alo,
                  const unsigned short* __restrict__ Bhi,
                  const unsigned short* __restrict__ Blo,
                  const float* __restrict__ bias,
                  const float* __restrict__ u,    // u1[256] then u2[256]
                  float* __restrict__ sp,         // [2][N_NODES] partials by bcol
                  float* __restrict__ tp) {
    __shared__ unsigned short sA[2][BM * BK];  // [hi/lo][row][k]
    __shared__ unsigned short sB[2][BN * BK];
    __shared__ float sred[BM], tred[BM];
    int tid = threadIdx.x;
    int br = blockIdx.x, bc = blockIdx.y;
    int lane = tid & 63, wv = tid >> 6;
    int wm = (wv >> 1) * 64, wn = (wv & 1) * 64;
    int q = lane >> 4, r = lane & 15;

    float biasv[4], u1v[4], u2v[4];
    #pragma unroll
    for (int nt = 0; nt < 4; nt++) {
        int gc = bc * BN + wn + nt * 16 + r;
        biasv[nt] = bias[gc];
        u1v[nt] = u[gc];
        u2v[nt] = u[256 + gc];
    }
    if (tid < BM) { sred[tid] = 0.f; tred[tid] = 0.f; }

    floatx4 acc[4][4] = {};

    const size_t arow0 = (size_t)br * BM;
    const int brow0 = bc * BN;
    int seg = lane & 3;               // 16B segment within a 64B tile-row
    int rl16 = lane >> 2;             // row within a 16-row staging group

    for (int kt = 0; kt < K2 / BK; kt++) {
        #pragma unroll
        for (int t = 0; t < 2; t++) {
            int rloc = wv * 32 + t * 16 + rl16;
            size_t gA = (arow0 + rloc) * (size_t)K2 + kt * BK + seg * 8;
            size_t gB = (size_t)(brow0 + rloc) * K2 + kt * BK + seg * 8;
            int ldsoff = (wv * 32 + t * 16) * BK;   // wave-uniform base (ushorts)
            load_lds16(Ahi + gA, &sA[0][ldsoff]);
            load_lds16(Alo + gA, &sA[1][ldsoff]);
            load_lds16(Bhi + gB, &sB[0][ldsoff]);
            load_lds16(Blo + gB, &sB[1][ldsoff]);
        }
        __syncthreads();
        short8 ah[4], al[4], bh[4], bl[4];
        #pragma unroll
        for (int i = 0; i < 4; i++) {
            ah[i] = *(const short8*)&sA[0][(wm + i * 16 + r) * BK + q * 8];
            al[i] = *(const short8*)&sA[1][(wm + i * 16 + r) * BK + q * 8];
            bh[i] = *(const short8*)&sB[0][(wn + i * 16 + r) * BK + q * 8];
            bl[i] = *(const short8*)&sB[1][(wn + i * 16 + r) * BK + q * 8];
        }
        #pragma unroll
        for (int mt = 0; mt < 4; mt++)
            #pragma unroll
            for (int nt = 0; nt < 4; nt++) {
                acc[mt][nt] = __builtin_amdgcn_mfma_f32_16x16x32_bf16(ah[mt], bh[nt], acc[mt][nt], 0, 0, 0);
                acc[mt][nt] = __builtin_amdgcn_mfma_f32_16x16x32_bf16(ah[mt], bl[nt], acc[mt][nt], 0, 0, 0);
                acc[mt][nt] = __builtin_amdgcn_mfma_f32_16x16x32_bf16(al[mt], bh[nt], acc[mt][nt], 0, 0, 0);
            }
        __syncthreads();
    }

    // epilogue: per-row s,t partials (C/D layout: col=r, row=q*4+reg)
    #pragma unroll
    for (int mt = 0; mt < 4; mt++) {
        #pragma unroll
        for (int reg = 0; reg < 4; reg++) {
            float sacc = 0.f, tacc = 0.f;
            #pragma unroll
            for (int nt = 0; nt < 4; nt++) {
                float h = fmaxf(acc[mt][nt][reg] + biasv[nt], 0.f);
                sacc += h * u1v[nt];
                tacc += h * u2v[nt];
            }
            #pragma unroll
            for (int off = 1; off < 16; off <<= 1) {
                sacc += __shfl_xor(sacc, off);
                tacc += __shfl_xor(tacc, off);
            }
            if (r == 0) {
                int row = wm + mt * 16 + q * 4 + reg;
                atomicAdd(&sred[row], sacc);
                atomicAdd(&tred[row], tacc);
            }
        }
    }
    __syncthreads();
    if (tid < BM) {
        size_t grow = arow0 + tid;
        if (grow < N_NODES) {
            sp[(size_t)bc * N_NODES + grow] = sred[tid];
            tp[(size_t)bc * N_NODES + grow] = tred[tid];
        }
    }
}

// ---------------- combine col-block partials ----------------
__global__ void k_comb(const float* __restrict__ sp, const float* __restrict__ tp,
                       float* __restrict__ s, float* __restrict__ t_) {
    int i = blockIdx.x * blockDim.x + threadIdx.x;
    if (i < N_NODES) {
        s[i] = sp[i] + sp[N_NODES + i];
        t_[i] = tp[i] + tp[N_NODES + i];
    }
}

// ---------------- logits: gather s over CSR row + t + c ----------------
__global__ void k_logits(const int* __restrict__ deg, const int* __restrict__ cursor,
                         const int* __restrict__ csr,
                         const float* __restrict__ s, const float* __restrict__ t_,
                         const float* __restrict__ cptr, float* __restrict__ logits) {
    int i = blockIdx.x * blockDim.x + threadIdx.x;
    if (i >= N_NODES) return;
    int d = deg[i];
    int end = cursor[i];
    int start = end - d;
    float sum = 0.f;
    for (int j = start; j < end; j++) sum += s[csr[j]];
    logits[i] = sum / fmaxf((float)d, 1.0f) + t_[i] + cptr[0];
}

// ---------------- softmax over N (single block) ----------------
__global__ __launch_bounds__(1024) void k_softmax(const float* __restrict__ logits,
                                                  float* __restrict__ out) {
    __shared__ float red[1024];
    int t = threadIdx.x;
    float mx = -INFINITY;
    for (int i = t; i < N_NODES; i += 1024) mx = fmaxf(mx, logits[i]);
    red[t] = mx;
    __syncthreads();
    for (int o = 512; o; o >>= 1) {
        if (t < o) red[t] = fmaxf(red[t], red[t + o]);
        __syncthreads();
    }
    float gmax = red[0];
    __syncthreads();
    float sm = 0.f;
    for (int i = t; i < N_NODES; i += 1024) sm += __expf(logits[i] - gmax);
    red[t] = sm;
    __syncthreads();
    for (int o = 512; o; o >>= 1) {
        if (t < o) red[t] += red[t + o];
        __syncthreads();
    }
    float inv = 1.0f / red[0];
    for (int i = t; i < N_NODES; i += 1024) out[i] = __expf(logits[i] - gmax) * inv;
}

extern "C" void kernel_launch(void* const* d_in, const int* in_sizes, int n_in,
                              void* d_out, int out_size, void* d_ws, size_t ws_size,
                              hipStream_t stream) {
    const float* x   = (const float*)d_in[0];
    const int*   ei  = (const int*)d_in[1];
    const int*   src = ei;
    const int*   dst = ei + N_EDGES;
    const int*   mention = (const int*)d_in[2];
    const float* W1l = (const float*)d_in[3];
    const float* b1  = (const float*)d_in[4];
    const float* W1r = (const float*)d_in[5];
    const float* W2l = (const float*)d_in[6];
    const float* b2  = (const float*)d_in[7];
    const float* W2r = (const float*)d_in[8];

    char* w = (char*)d_ws;
    unsigned short* Ahi = (unsigned short*)w;  w += (size_t)M_PAD * K2 * 2;
    unsigned short* Alo = (unsigned short*)w;  w += (size_t)M_PAD * K2 * 2;
    unsigned short* Bhi = (unsigned short*)w;  w += (size_t)256 * K2 * 2;
    unsigned short* Blo = (unsigned short*)w;  w += (size_t)256 * K2 * 2;
    float* sp    = (float*)w;  w += (size_t)2 * N_NODES * 4;
    float* tp    = (float*)w;  w += (size_t)2 * N_NODES * 4;
    float* s     = (float*)w;  w += (size_t)N_NODES * 4;
    float* t_    = (float*)w;  w += (size_t)N_NODES * 4;
    float* logit = (float*)w;  w += (size_t)N_NODES * 4;
    float* h1m   = (float*)w;  w += (size_t)256 * D * 4;
    float* v     = (float*)w;  w += D * 4;
    float* u     = (float*)w;  w += 2 * D * 4;
    float* c     = (float*)w;  w += 16;
    int* deg     = (int*)w;    w += (size_t)N_NODES * 4;
    int* cursor  = (int*)w;    w += (size_t)N_NODES * 4;
    int* csr     = (int*)w;    w += (size_t)N_EDGES * 4;

    hipMemsetAsync(deg, 0, N_NODES * sizeof(int), stream);

    k_count <<<(N_EDGES + 255) / 256, 256, 0, stream>>>(dst, deg);
    k_scan  <<<1, 1024, 0, stream>>>(deg, cursor);
    k_bucket<<<(N_EDGES + 255) / 256, 256, 0, stream>>>(src, dst, cursor, csr);

    k_splitX<<<(N_NODES * 64 + 255) / 256, 256, 0, stream>>>(x, Ahi, Alo);
    k_splitB<<<(256 * 128 + 255) / 256, 256, 0, stream>>>(W1l, W1r, Bhi, Blo);
    k_agg   <<<(N_NODES + 3) / 4, 256, 0, stream>>>(cursor, deg, csr, Ahi, Alo);

    k_small <<<256, 256, 0, stream>>>(mention, deg, cursor, csr, x, W1l, W1r, b1, h1m);
    k_v     <<<1, 256, 0, stream>>>(mention, deg, h1m, W2l, W2r, b2, v, c);
    k_u     <<<1, 256, 0, stream>>>(W2l, W2r, v, u);

    dim3 g1(M_PAD / BM, 2);
    k_gemm_fused<<<g1, 256, 0, stream>>>(Ahi, Alo, Bhi, Blo, b1, u, sp, tp);

    k_comb  <<<(N_NODES + 255) / 256, 256, 0, stream>>>(sp, tp, s, t_);
    k_logits<<<(N_NODES + 255) / 256, 256, 0, stream>>>(deg, cursor, csr, s, t_, c, logit);
    k_softmax<<<1, 1024, 0, stream>>>(logit, (float*)d_out);
}

// Round 4
// 406.137 us; speedup vs baseline: 7.8449x; 1.1986x over previous
//
#include <hip/hip_runtime.h>
#include <math.h>

#define N_NODES 50000
#define N_EDGES 800000
#define D 256
#define K2 512        // concat [mean | x] feature dim
#define M_PAD 50048   // 391 * 128 rows (GEMM padding)
#define BM 128
#define BN 128
#define BK 32
#define SCAN_B 196    // ceil(N_NODES/256)
#define SM_B 49       // ceil(N_NODES/1024)

typedef __attribute__((ext_vector_type(8))) short short8;
typedef __attribute__((ext_vector_type(4))) float floatx4;

__device__ __forceinline__ unsigned short bf16_rn(float f) {
    union { float f; unsigned u; } a; a.f = f;
    unsigned r = a.u + 0x7FFF + ((a.u >> 16) & 1);
    return (unsigned short)(r >> 16);
}
__device__ __forceinline__ float bf16_to_f(unsigned short h) {
    union { unsigned u; float f; } a; a.u = ((unsigned)h) << 16;
    return a.f;
}
__device__ __forceinline__ void load_lds16(const void* g, void* lds) {
    __builtin_amdgcn_global_load_lds((const __attribute__((address_space(1))) void*)g,
                                     (__attribute__((address_space(3))) void*)lds, 16, 0, 0);
}

// ---------------- CSR build ----------------
__global__ void k_count(const int* __restrict__ dst, int* __restrict__ deg) {
    int e = blockIdx.x * blockDim.x + threadIdx.x;
    if (e < N_EDGES) atomicAdd(&deg[dst[e]], 1);
}

// phase 1: per-block sums
__global__ void k_scan1(const int* __restrict__ deg, int* __restrict__ bsum) {
    __shared__ int red[256];
    int b = blockIdx.x, t = threadIdx.x;
    int i = b * 256 + t;
    red[t] = (i < N_NODES) ? deg[i] : 0;
    __syncthreads();
    for (int o = 128; o; o >>= 1) {
        if (t < o) red[t] += red[t + o];
        __syncthreads();
    }
    if (t == 0) bsum[b] = red[0];
}

// phase 2: single-block exclusive scan of 196 block sums
__global__ void k_scan2(const int* __restrict__ bsum, int* __restrict__ boff) {
    __shared__ int sh[256];
    int t = threadIdx.x;
    sh[t] = (t < SCAN_B) ? bsum[t] : 0;
    __syncthreads();
    for (int o = 1; o < 256; o <<= 1) {
        int v = (t >= o) ? sh[t - o] : 0;
        __syncthreads();
        sh[t] += v;
        __syncthreads();
    }
    boff[t] = (t == 0) ? 0 : sh[t - 1];
}

// phase 3: per-block exclusive scan + offset -> cursor (row starts)
__global__ void k_scan3(const int* __restrict__ deg, const int* __restrict__ boff,
                        int* __restrict__ cursor) {
    __shared__ int sh[256];
    int b = blockIdx.x, t = threadIdx.x;
    int i = b * 256 + t;
    int v = (i < N_NODES) ? deg[i] : 0;
    sh[t] = v;
    __syncthreads();
    for (int o = 1; o < 256; o <<= 1) {
        int val = (t >= o) ? sh[t - o] : 0;
        __syncthreads();
        sh[t] += val;
        __syncthreads();
    }
    if (i < N_NODES) cursor[i] = boff[b] + sh[t] - v;
}

// after this, cursor[i] == row END; start = cursor[i]-deg[i]
__global__ void k_bucket(const int* __restrict__ src, const int* __restrict__ dst,
                         int* __restrict__ cursor, int* __restrict__ csr_src) {
    int e = blockIdx.x * blockDim.x + threadIdx.x;
    if (e >= N_EDGES) return;
    int pos = atomicAdd(&cursor[dst[e]], 1);
    csr_src[pos] = src[e];
}

// ---------------- split x into bf16 hi/lo halves of A ----------------
__global__ void k_splitX(const float* __restrict__ x, unsigned short* __restrict__ Ahi,
                         unsigned short* __restrict__ Alo) {
    int t = blockIdx.x * blockDim.x + threadIdx.x;  // over N*64
    if (t >= N_NODES * 64) return;
    int m = t >> 6, j = (t & 63) * 4;
    float4 v = *(const float4*)&x[(size_t)m * D + j];
    ushort4 hi, lo;
    hi.x = bf16_rn(v.x); lo.x = bf16_rn(v.x - bf16_to_f(hi.x));
    hi.y = bf16_rn(v.y); lo.y = bf16_rn(v.y - bf16_to_f(hi.y));
    hi.z = bf16_rn(v.z); lo.z = bf16_rn(v.z - bf16_to_f(hi.z));
    hi.w = bf16_rn(v.w); lo.w = bf16_rn(v.w - bf16_to_f(hi.w));
    *(ushort4*)&Ahi[(size_t)m * K2 + 256 + j] = hi;
    *(ushort4*)&Alo[(size_t)m * K2 + 256 + j] = lo;
}

// ---------------- split [W1l|W1r] into bf16 hi/lo B ----------------
__global__ void k_splitB(const float* __restrict__ Wl, const float* __restrict__ Wr,
                         unsigned short* __restrict__ Bhi, unsigned short* __restrict__ Blo) {
    int t = blockIdx.x * blockDim.x + threadIdx.x;  // over 256*128
    if (t >= 256 * 128) return;
    int n = t >> 7, k = (t & 127) * 4;
    const float* srcp = (k < 256) ? &Wl[(size_t)n * 256 + k] : &Wr[(size_t)n * 256 + k - 256];
    float4 v = *(const float4*)srcp;
    ushort4 hi, lo;
    hi.x = bf16_rn(v.x); lo.x = bf16_rn(v.x - bf16_to_f(hi.x));
    hi.y = bf16_rn(v.y); lo.y = bf16_rn(v.y - bf16_to_f(hi.y));
    hi.z = bf16_rn(v.z); lo.z = bf16_rn(v.z - bf16_to_f(hi.z));
    hi.w = bf16_rn(v.w); lo.w = bf16_rn(v.w - bf16_to_f(hi.w));
    *(ushort4*)&Bhi[(size_t)n * K2 + k] = hi;
    *(ushort4*)&Blo[(size_t)n * K2 + k] = lo;
}

// ---------------- mean aggregation (gathers bf16 xhi, writes mean hi/lo) ----------------
__global__ __launch_bounds__(256) void k_agg(const int* __restrict__ cursor,
                                             const int* __restrict__ deg,
                                             const int* __restrict__ csr,
                                             unsigned short* __restrict__ Ahi,
                                             unsigned short* __restrict__ Alo) {
    int node = blockIdx.x * 4 + (threadIdx.x >> 6);
    int lane = threadIdx.x & 63;
    if (node >= N_NODES) return;
    int d = deg[node], end = cursor[node], start = end - d;
    float a0 = 0, a1 = 0, a2 = 0, a3 = 0, b0 = 0, b1 = 0, b2 = 0, b3 = 0;
    int j = start;
    for (; j + 2 <= end; j += 2) {
        int s0 = csr[j], s1 = csr[j + 1];
        ushort4 v0 = *(const ushort4*)&Ahi[(size_t)s0 * K2 + 256 + lane * 4];
        ushort4 v1 = *(const ushort4*)&Ahi[(size_t)s1 * K2 + 256 + lane * 4];
        a0 += bf16_to_f(v0.x); a1 += bf16_to_f(v0.y); a2 += bf16_to_f(v0.z); a3 += bf16_to_f(v0.w);
        b0 += bf16_to_f(v1.x); b1 += bf16_to_f(v1.y); b2 += bf16_to_f(v1.z); b3 += bf16_to_f(v1.w);
    }
    if (j < end) {
        int s0 = csr[j];
        ushort4 v0 = *(const ushort4*)&Ahi[(size_t)s0 * K2 + 256 + lane * 4];
        a0 += bf16_to_f(v0.x); a1 += bf16_to_f(v0.y); a2 += bf16_to_f(v0.z); a3 += bf16_to_f(v0.w);
    }
    float inv = 1.0f / fmaxf((float)d, 1.0f);
    float m0 = (a0 + b0) * inv, m1 = (a1 + b1) * inv, m2 = (a2 + b2) * inv, m3 = (a3 + b3) * inv;
    ushort4 hi, lo;
    hi.x = bf16_rn(m0); lo.x = bf16_rn(m0 - bf16_to_f(hi.x));
    hi.y = bf16_rn(m1); lo.y = bf16_rn(m1 - bf16_to_f(hi.y));
    hi.z = bf16_rn(m2); lo.z = bf16_rn(m2 - bf16_to_f(hi.z));
    hi.w = bf16_rn(m3); lo.w = bf16_rn(m3 - bf16_to_f(hi.w));
    *(ushort4*)&Ahi[(size_t)node * K2 + lane * 4] = hi;
    *(ushort4*)&Alo[(size_t)node * K2 + lane * 4] = lo;
}

// ---------------- exact fp32 h1 rows for mention + its neighbors ----------------
__global__ __launch_bounds__(256) void k_small(const int* __restrict__ mention,
                                               const int* __restrict__ deg,
                                               const int* __restrict__ cursor,
                                               const int* __restrict__ csr,
                                               const float* __restrict__ x,
                                               const float* __restrict__ W1l,
                                               const float* __restrict__ W1r,
                                               const float* __restrict__ b1,
                                               float* __restrict__ h1m) {
    int m = mention[0];
    int dm = min(deg[m], 255);
    int slot = blockIdx.x;
    if (slot > dm) return;
    int startm = cursor[m] - deg[m];
    int node = (slot == 0) ? m : csr[startm + slot - 1];
    __shared__ float smean[D], sx[D];
    int t = threadIdx.x;
    int d = deg[node], end = cursor[node], start = end - d;
    float a = 0.f;
    for (int j = start; j < end; j++) a += x[(size_t)csr[j] * D + t];
    smean[t] = a / fmaxf((float)d, 1.0f);
    sx[t] = x[(size_t)node * D + t];
    __syncthreads();
    float z = b1[t];
    for (int k = 0; k < D; k++)
        z += smean[k] * W1l[(size_t)t * D + k] + sx[k] * W1r[(size_t)t * D + k];
    h1m[(size_t)slot * D + t] = fmaxf(z, 0.f);
}

// ---------------- v = h2[mention] (fp32 exact); c = b2 . v ----------------
__global__ __launch_bounds__(256) void k_v(const int* __restrict__ mention,
                                           const int* __restrict__ deg,
                                           const float* __restrict__ h1m,
                                           const float* __restrict__ W2l,
                                           const float* __restrict__ W2r,
                                           const float* __restrict__ b2,
                                           float* __restrict__ v,
                                           float* __restrict__ cout) {
    __shared__ float sm[D], sh[D], red[256];
    int m = mention[0];
    int dm = min(deg[m], 255);
    int t = threadIdx.x;
    float a = 0.f;
    for (int j = 1; j <= dm; j++) a += h1m[(size_t)j * D + t];
    sm[t] = a / fmaxf((float)deg[m], 1.0f);
    sh[t] = h1m[t];
    __syncthreads();
    float acc = b2[t];
    for (int k = 0; k < D; k++)
        acc += sm[k] * W2l[(size_t)t * D + k] + sh[k] * W2r[(size_t)t * D + k];
    v[t] = acc;
    red[t] = b2[t] * acc;
    __syncthreads();
    for (int o = 128; o; o >>= 1) {
        if (t < o) red[t] += red[t + o];
        __syncthreads();
    }
    if (t == 0) cout[0] = red[0];
}

// ---------------- u1 = W2l^T v, u2 = W2r^T v ----------------
__global__ __launch_bounds__(256) void k_u(const float* __restrict__ W2l,
                                           const float* __restrict__ W2r,
                                           const float* __restrict__ v,
                                           float* __restrict__ u) {
    __shared__ float sv[D];
    int k = threadIdx.x;
    sv[k] = v[k];
    __syncthreads();
    float a1 = 0.f, a2 = 0.f;
    for (int n = 0; n < D; n++) {
        a1 += W2l[(size_t)n * D + k] * sv[n];
        a2 += W2r[(size_t)n * D + k] * sv[n];
    }
    u[k] = a1;
    u[D + k] = a2;
}

// ---------------- fused split-bf16 MFMA GEMM + relu + projection epilogue ----------------
__global__ __launch_bounds__(256, 2)
void k_gemm_fused(const unsigned short* __restrict__ Ahi,
                  const unsigned short* __restrict__ Alo,
                  const unsigned short* __restrict__ Bhi,
                  const unsigned short* __restrict__ Blo,
                  const float* __restrict__ bias,
                  const float* __restrict__ u,    // u1[256] then u2[256]
                  float* __restrict__ sp,         // [2][N_NODES] partials by bcol
                  float* __restrict__ tp) {
    __shared__ unsigned short sA[2][BM * BK];
    __shared__ unsigned short sB[2][BN * BK];
    __shared__ float sred[BM], tred[BM];
    int tid = threadIdx.x;
    int br = blockIdx.x, bc = blockIdx.y;
    int lane = tid & 63, wv = tid >> 6;
    int wm = (wv >> 1) * 64, wn = (wv & 1) * 64;
    int q = lane >> 4, r = lane & 15;

    float biasv[4], u1v[4], u2v[4];
    #pragma unroll
    for (int nt = 0; nt < 4; nt++) {
        int gc = bc * BN + wn + nt * 16 + r;
        biasv[nt] = bias[gc];
        u1v[nt] = u[gc];
        u2v[nt] = u[256 + gc];
    }
    if (tid < BM) { sred[tid] = 0.f; tred[tid] = 0.f; }

    floatx4 acc[4][4] = {};

    const size_t arow0 = (size_t)br * BM;
    const int brow0 = bc * BN;
    int seg = lane & 3;
    int rl16 = lane >> 2;

    for (int kt = 0; kt < K2 / BK; kt++) {
        #pragma unroll
        for (int t = 0; t < 2; t++) {
            int rloc = wv * 32 + t * 16 + rl16;
            size_t gA = (arow0 + rloc) * (size_t)K2 + kt * BK + seg * 8;
            size_t gB = (size_t)(brow0 + rloc) * K2 + kt * BK + seg * 8;
            int ldsoff = (wv * 32 + t * 16) * BK;
            load_lds16(Ahi + gA, &sA[0][ldsoff]);
            load_lds16(Alo + gA, &sA[1][ldsoff]);
            load_lds16(Bhi + gB, &sB[0][ldsoff]);
            load_lds16(Blo + gB, &sB[1][ldsoff]);
        }
        __syncthreads();
        short8 ah[4], al[4], bh[4], bl[4];
        #pragma unroll
        for (int i = 0; i < 4; i++) {
            ah[i] = *(const short8*)&sA[0][(wm + i * 16 + r) * BK + q * 8];
            al[i] = *(const short8*)&sA[1][(wm + i * 16 + r) * BK + q * 8];
            bh[i] = *(const short8*)&sB[0][(wn + i * 16 + r) * BK + q * 8];
            bl[i] = *(const short8*)&sB[1][(wn + i * 16 + r) * BK + q * 8];
        }
        #pragma unroll
        for (int mt = 0; mt < 4; mt++)
            #pragma unroll
            for (int nt = 0; nt < 4; nt++) {
                acc[mt][nt] = __builtin_amdgcn_mfma_f32_16x16x32_bf16(ah[mt], bh[nt], acc[mt][nt], 0, 0, 0);
                acc[mt][nt] = __builtin_amdgcn_mfma_f32_16x16x32_bf16(ah[mt], bl[nt], acc[mt][nt], 0, 0, 0);
                acc[mt][nt] = __builtin_amdgcn_mfma_f32_16x16x32_bf16(al[mt], bh[nt], acc[mt][nt], 0, 0, 0);
            }
        __syncthreads();
    }

    #pragma unroll
    for (int mt = 0; mt < 4; mt++) {
        #pragma unroll
        for (int reg = 0; reg < 4; reg++) {
            float sacc = 0.f, tacc = 0.f;
            #pragma unroll
            for (int nt = 0; nt < 4; nt++) {
                float h = fmaxf(acc[mt][nt][reg] + biasv[nt], 0.f);
                sacc += h * u1v[nt];
                tacc += h * u2v[nt];
            }
            #pragma unroll
            for (int off = 1; off < 16; off <<= 1) {
                sacc += __shfl_xor(sacc, off);
                tacc += __shfl_xor(tacc, off);
            }
            if (r == 0) {
                int row = wm + mt * 16 + q * 4 + reg;
                atomicAdd(&sred[row], sacc);
                atomicAdd(&tred[row], tacc);
            }
        }
    }
    __syncthreads();
    if (tid < BM) {
        size_t grow = arow0 + tid;
        if (grow < N_NODES) {
            sp[(size_t)bc * N_NODES + grow] = sred[tid];
            tp[(size_t)bc * N_NODES + grow] = tred[tid];
        }
    }
}

// ---------------- combine col-block partials ----------------
__global__ void k_comb(const float* __restrict__ sp, const float* __restrict__ tp,
                       float* __restrict__ s, float* __restrict__ t_) {
    int i = blockIdx.x * blockDim.x + threadIdx.x;
    if (i < N_NODES) {
        s[i] = sp[i] + sp[N_NODES + i];
        t_[i] = tp[i] + tp[N_NODES + i];
    }
}

// ---------------- logits: gather s over CSR row + t + c ----------------
__global__ void k_logits(const int* __restrict__ deg, const int* __restrict__ cursor,
                         const int* __restrict__ csr,
                         const float* __restrict__ s, const float* __restrict__ t_,
                         const float* __restrict__ cptr, float* __restrict__ logits) {
    int i = blockIdx.x * blockDim.x + threadIdx.x;
    if (i >= N_NODES) return;
    int d = deg[i];
    int end = cursor[i];
    int start = end - d;
    float sum = 0.f;
    for (int j = start; j < end; j++) sum += s[csr[j]];
    logits[i] = sum / fmaxf((float)d, 1.0f) + t_[i] + cptr[0];
}

// ---------------- multi-block softmax ----------------
// phase 1: per-block max + sum(exp(x - mb))
__global__ __launch_bounds__(1024) void k_sm1(const float* __restrict__ logits,
                                              float* __restrict__ pmax,
                                              float* __restrict__ psum) {
    __shared__ float red[1024];
    int b = blockIdx.x, t = threadIdx.x;
    int i = b * 1024 + t;
    float x = (i < N_NODES) ? logits[i] : -INFINITY;
    red[t] = x;
    __syncthreads();
    for (int o = 512; o; o >>= 1) {
        if (t < o) red[t] = fmaxf(red[t], red[t + o]);
        __syncthreads();
    }
    float mb = red[0];
    __syncthreads();
    red[t] = (i < N_NODES) ? __expf(x - mb) : 0.f;
    __syncthreads();
    for (int o = 512; o; o >>= 1) {
        if (t < o) red[t] += red[t + o];
        __syncthreads();
    }
    if (t == 0) { pmax[b] = mb; psum[b] = red[0]; }
}

// phase 2: combine partials -> g, invS
__global__ void k_sm2(const float* __restrict__ pmax, const float* __restrict__ psum,
                      float* __restrict__ gS) {
    __shared__ float rm[64], rs[64];
    int t = threadIdx.x;
    float m = (t < SM_B) ? pmax[t] : -INFINITY;
    rm[t] = m;
    __syncthreads();
    for (int o = 32; o; o >>= 1) {
        if (t < o) rm[t] = fmaxf(rm[t], rm[t + o]);
        __syncthreads();
    }
    float g = rm[0];
    __syncthreads();
    rs[t] = (t < SM_B) ? psum[t] * __expf(m - g) : 0.f;
    __syncthreads();
    for (int o = 32; o; o >>= 1) {
        if (t < o) rs[t] += rs[t + o];
        __syncthreads();
    }
    if (t == 0) { gS[0] = g; gS[1] = 1.0f / rs[0]; }
}

// phase 3: finalize
__global__ void k_sm3(const float* __restrict__ logits, const float* __restrict__ gS,
                      float* __restrict__ out) {
    int i = blockIdx.x * blockDim.x + threadIdx.x;
    if (i < N_NODES) out[i] = __expf(logits[i] - gS[0]) * gS[1];
}

extern "C" void kernel_launch(void* const* d_in, const int* in_sizes, int n_in,
                              void* d_out, int out_size, void* d_ws, size_t ws_size,
                              hipStream_t stream) {
    const float* x   = (const float*)d_in[0];
    const int*   ei  = (const int*)d_in[1];
    const int*   src = ei;
    const int*   dst = ei + N_EDGES;
    const int*   mention = (const int*)d_in[2];
    const float* W1l = (const float*)d_in[3];
    const float* b1  = (const float*)d_in[4];
    const float* W1r = (const float*)d_in[5];
    const float* W2l = (const float*)d_in[6];
    const float* b2  = (const float*)d_in[7];
    const float* W2r = (const float*)d_in[8];

    char* w = (char*)d_ws;
    unsigned short* Ahi = (unsigned short*)w;  w += (size_t)M_PAD * K2 * 2;
    unsigned short* Alo = (unsigned short*)w;  w += (size_t)M_PAD * K2 * 2;
    unsigned short* Bhi = (unsigned short*)w;  w += (size_t)256 * K2 * 2;
    unsigned short* Blo = (unsigned short*)w;  w += (size_t)256 * K2 * 2;
    float* sp    = (float*)w;  w += (size_t)2 * N_NODES * 4;
    float* tp    = (float*)w;  w += (size_t)2 * N_NODES * 4;
    float* s     = (float*)w;  w += (size_t)N_NODES * 4;
    float* t_    = (float*)w;  w += (size_t)N_NODES * 4;
    float* logit = (float*)w;  w += (size_t)N_NODES * 4;
    float* h1m   = (float*)w;  w += (size_t)256 * D * 4;
    float* v     = (float*)w;  w += D * 4;
    float* u     = (float*)w;  w += 2 * D * 4;
    float* c     = (float*)w;  w += 16;
    float* pmax  = (float*)w;  w += 64 * 4;
    float* psum  = (float*)w;  w += 64 * 4;
    float* gS    = (float*)w;  w += 16;
    int* deg     = (int*)w;    w += (size_t)N_NODES * 4;
    int* cursor  = (int*)w;    w += (size_t)N_NODES * 4;
    int* bsum    = (int*)w;    w += 256 * 4;
    int* boff    = (int*)w;    w += 256 * 4;
    int* csr     = (int*)w;    w += (size_t)N_EDGES * 4;

    hipMemsetAsync(deg, 0, N_NODES * sizeof(int), stream);

    k_count <<<(N_EDGES + 255) / 256, 256, 0, stream>>>(dst, deg);
    k_scan1 <<<SCAN_B, 256, 0, stream>>>(deg, bsum);
    k_scan2 <<<1, 256, 0, stream>>>(bsum, boff);
    k_scan3 <<<SCAN_B, 256, 0, stream>>>(deg, boff, cursor);
    k_bucket<<<(N_EDGES + 255) / 256, 256, 0, stream>>>(src, dst, cursor, csr);

    k_splitX<<<(N_NODES * 64 + 255) / 256, 256, 0, stream>>>(x, Ahi, Alo);
    k_splitB<<<(256 * 128 + 255) / 256, 256, 0, stream>>>(W1l, W1r, Bhi, Blo);
    k_agg   <<<(N_NODES + 3) / 4, 256, 0, stream>>>(cursor, deg, csr, Ahi, Alo);

    k_small <<<256, 256, 0, stream>>>(mention, deg, cursor, csr, x, W1l, W1r, b1, h1m);
    k_v     <<<1, 256, 0, stream>>>(mention, deg, h1m, W2l, W2r, b2, v, c);
    k_u     <<<1, 256, 0, stream>>>(W2l, W2r, v, u);

    dim3 g1(M_PAD / BM, 2);
    k_gemm_fused<<<g1, 256, 0, stream>>>(Ahi, Alo, Bhi, Blo, b1, u, sp, tp);

    k_comb  <<<(N_NODES + 255) / 256, 256, 0, stream>>>(sp, tp, s, t_);
    k_logits<<<(N_NODES + 255) / 256, 256, 0, stream>>>(deg, cursor, csr, s, t_, c, logit);
    k_sm1   <<<SM_B, 1024, 0, stream>>>(logit, pmax, psum);
    k_sm2   <<<1, 64, 0, stream>>>(pmax, psum, gS);
    k_sm3   <<<(N_NODES + 255) / 256, 256, 0, stream>>>(logit, gS, (float*)d_out);
}

// Round 5
// 388.989 us; speedup vs baseline: 8.1907x; 1.0441x over previous
//
#include <hip/hip_runtime.h>
#include <math.h>

#define N_NODES 50000
#define N_EDGES 800000
#define D 256
#define K2 512        // concat [mean | x] feature dim
#define M_PAD 50048   // 391 * 128 rows (GEMM padding)
#define BM 128
#define BN 128
#define BK 32
#define SCAN_B 196    // ceil(N_NODES/256)
#define SM_B 49       // ceil(N_NODES/1024)

typedef __attribute__((ext_vector_type(8))) short short8;
typedef __attribute__((ext_vector_type(8))) unsigned short ushort8;
typedef __attribute__((ext_vector_type(4))) float floatx4;

__device__ __forceinline__ unsigned short bf16_rn(float f) {
    union { float f; unsigned u; } a; a.f = f;
    unsigned r = a.u + 0x7FFF + ((a.u >> 16) & 1);
    return (unsigned short)(r >> 16);
}
__device__ __forceinline__ float bf16_to_f(unsigned short h) {
    union { unsigned u; float f; } a; a.u = ((unsigned)h) << 16;
    return a.f;
}
__device__ __forceinline__ void load_lds16(const void* g, void* lds) {
    __builtin_amdgcn_global_load_lds((const __attribute__((address_space(1))) void*)g,
                                     (__attribute__((address_space(3))) void*)lds, 16, 0, 0);
}

// ---------------- CSR build ----------------
__global__ void k_count(const int* __restrict__ dst, int* __restrict__ deg) {
    int e = blockIdx.x * blockDim.x + threadIdx.x;
    if (e < N_EDGES) atomicAdd(&deg[dst[e]], 1);
}

__global__ void k_scan1(const int* __restrict__ deg, int* __restrict__ bsum) {
    __shared__ int red[256];
    int b = blockIdx.x, t = threadIdx.x;
    int i = b * 256 + t;
    red[t] = (i < N_NODES) ? deg[i] : 0;
    __syncthreads();
    for (int o = 128; o; o >>= 1) {
        if (t < o) red[t] += red[t + o];
        __syncthreads();
    }
    if (t == 0) bsum[b] = red[0];
}

__global__ void k_scan2(const int* __restrict__ bsum, int* __restrict__ boff) {
    __shared__ int sh[256];
    int t = threadIdx.x;
    sh[t] = (t < SCAN_B) ? bsum[t] : 0;
    __syncthreads();
    for (int o = 1; o < 256; o <<= 1) {
        int v = (t >= o) ? sh[t - o] : 0;
        __syncthreads();
        sh[t] += v;
        __syncthreads();
    }
    boff[t] = (t == 0) ? 0 : sh[t - 1];
}

__global__ void k_scan3(const int* __restrict__ deg, const int* __restrict__ boff,
                        int* __restrict__ cursor) {
    __shared__ int sh[256];
    int b = blockIdx.x, t = threadIdx.x;
    int i = b * 256 + t;
    int v = (i < N_NODES) ? deg[i] : 0;
    sh[t] = v;
    __syncthreads();
    for (int o = 1; o < 256; o <<= 1) {
        int val = (t >= o) ? sh[t - o] : 0;
        __syncthreads();
        sh[t] += val;
        __syncthreads();
    }
    if (i < N_NODES) cursor[i] = boff[b] + sh[t] - v;
}

// after this, cursor[i] == row END; start = cursor[i]-deg[i]
__global__ void k_bucket(const int* __restrict__ src, const int* __restrict__ dst,
                         int* __restrict__ cursor, int* __restrict__ csr_src) {
    int e = blockIdx.x * blockDim.x + threadIdx.x;
    if (e >= N_EDGES) return;
    int pos = atomicAdd(&cursor[dst[e]], 1);
    csr_src[pos] = src[e];
}

// ---------------- split x into bf16 hi/lo halves of A ----------------
__global__ void k_splitX(const float* __restrict__ x, unsigned short* __restrict__ Ahi,
                         unsigned short* __restrict__ Alo) {
    int t = blockIdx.x * blockDim.x + threadIdx.x;  // over N*64
    if (t >= N_NODES * 64) return;
    int m = t >> 6, j = (t & 63) * 4;
    float4 v = *(const float4*)&x[(size_t)m * D + j];
    ushort4 hi, lo;
    hi.x = bf16_rn(v.x); lo.x = bf16_rn(v.x - bf16_to_f(hi.x));
    hi.y = bf16_rn(v.y); lo.y = bf16_rn(v.y - bf16_to_f(hi.y));
    hi.z = bf16_rn(v.z); lo.z = bf16_rn(v.z - bf16_to_f(hi.z));
    hi.w = bf16_rn(v.w); lo.w = bf16_rn(v.w - bf16_to_f(hi.w));
    *(ushort4*)&Ahi[(size_t)m * K2 + 256 + j] = hi;
    *(ushort4*)&Alo[(size_t)m * K2 + 256 + j] = lo;
}

// ---------------- split [W1l|W1r] into bf16 hi/lo B ----------------
__global__ void k_splitB(const float* __restrict__ Wl, const float* __restrict__ Wr,
                         unsigned short* __restrict__ Bhi, unsigned short* __restrict__ Blo) {
    int t = blockIdx.x * blockDim.x + threadIdx.x;  // over 256*128
    if (t >= 256 * 128) return;
    int n = t >> 7, k = (t & 127) * 4;
    const float* srcp = (k < 256) ? &Wl[(size_t)n * 256 + k] : &Wr[(size_t)n * 256 + k - 256];
    float4 v = *(const float4*)srcp;
    ushort4 hi, lo;
    hi.x = bf16_rn(v.x); lo.x = bf16_rn(v.x - bf16_to_f(hi.x));
    hi.y = bf16_rn(v.y); lo.y = bf16_rn(v.y - bf16_to_f(hi.y));
    hi.z = bf16_rn(v.z); lo.z = bf16_rn(v.z - bf16_to_f(hi.z));
    hi.w = bf16_rn(v.w); lo.w = bf16_rn(v.w - bf16_to_f(hi.w));
    *(ushort4*)&Bhi[(size_t)n * K2 + k] = hi;
    *(ushort4*)&Blo[(size_t)n * K2 + k] = lo;
}

// ---------------- mean aggregation: 2 edges/wave, 16B/lane, unroll 4 ----------------
__global__ __launch_bounds__(256) void k_agg(const int* __restrict__ cursor,
                                             const int* __restrict__ deg,
                                             const int* __restrict__ csr,
                                             unsigned short* __restrict__ Ahi,
                                             unsigned short* __restrict__ Alo) {
    int node = blockIdx.x * 4 + (threadIdx.x >> 6);
    int lane = threadIdx.x & 63;
    if (node >= N_NODES) return;
    int d = deg[node], end = cursor[node], start = end - d;
    int h = lane >> 5;            // which edge of the pair this half-wave handles
    int col = (lane & 31) * 8;    // 32 lanes x 8 bf16 = 256 features
    float acc0[8] = {}, acc1[8] = {};
    int j = start;
    for (; j + 4 <= end; j += 4) {
        int i0 = csr[j + h];
        int i1 = csr[j + 2 + h];
        ushort8 v0 = *(const ushort8*)&Ahi[(size_t)i0 * K2 + 256 + col];
        ushort8 v1 = *(const ushort8*)&Ahi[(size_t)i1 * K2 + 256 + col];
        #pragma unroll
        for (int k = 0; k < 8; k++) {
            acc0[k] += bf16_to_f(v0[k]);
            acc1[k] += bf16_to_f(v1[k]);
        }
    }
    if (j + 2 <= end) {
        int i0 = csr[j + h];
        ushort8 v0 = *(const ushort8*)&Ahi[(size_t)i0 * K2 + 256 + col];
        #pragma unroll
        for (int k = 0; k < 8; k++) acc0[k] += bf16_to_f(v0[k]);
        j += 2;
    }
    if (j < end && h == 0) {      // odd leftover edge: half-wave 0 only
        int i0 = csr[j];
        ushort8 v0 = *(const ushort8*)&Ahi[(size_t)i0 * K2 + 256 + col];
        #pragma unroll
        for (int k = 0; k < 8; k++) acc0[k] += bf16_to_f(v0[k]);
    }
    float inv = 1.0f / fmaxf((float)d, 1.0f);
    ushort8 hi, lo;
    #pragma unroll
    for (int k = 0; k < 8; k++) {
        float a = acc0[k] + acc1[k];
        a += __shfl_xor(a, 32);   // combine the two half-waves
        float m = a * inv;
        hi[k] = bf16_rn(m);
        lo[k] = bf16_rn(m - bf16_to_f(hi[k]));
    }
    if (h == 0) {                 // lanes 0..31 write the 512B row
        *(ushort8*)&Ahi[(size_t)node * K2 + col] = hi;
        *(ushort8*)&Alo[(size_t)node * K2 + col] = lo;
    }
}

// ---------------- exact fp32 h1 rows for mention + its neighbors ----------------
__global__ __launch_bounds__(256) void k_small(const int* __restrict__ mention,
                                               const int* __restrict__ deg,
                                               const int* __restrict__ cursor,
                                               const int* __restrict__ csr,
                                               const float* __restrict__ x,
                                               const float* __restrict__ W1l,
                                               const float* __restrict__ W1r,
                                               const float* __restrict__ b1,
                                               float* __restrict__ h1m) {
    int m = mention[0];
    int dm = min(deg[m], 255);
    int slot = blockIdx.x;
    if (slot > dm) return;
    int startm = cursor[m] - deg[m];
    int node = (slot == 0) ? m : csr[startm + slot - 1];
    __shared__ float smean[D], sx[D];
    int t = threadIdx.x;
    int d = deg[node], end = cursor[node], start = end - d;
    float a = 0.f;
    for (int j = start; j < end; j++) a += x[(size_t)csr[j] * D + t];
    smean[t] = a / fmaxf((float)d, 1.0f);
    sx[t] = x[(size_t)node * D + t];
    __syncthreads();
    float z = b1[t];
    for (int k = 0; k < D; k++)
        z += smean[k] * W1l[(size_t)t * D + k] + sx[k] * W1r[(size_t)t * D + k];
    h1m[(size_t)slot * D + t] = fmaxf(z, 0.f);
}

// ---------------- v = h2[mention]; c = b2.v; u1 = W2l^T v; u2 = W2r^T v ----------------
__global__ __launch_bounds__(256) void k_vu(const int* __restrict__ mention,
                                            const int* __restrict__ deg,
                                            const float* __restrict__ h1m,
                                            const float* __restrict__ W2l,
                                            const float* __restrict__ W2r,
                                            const float* __restrict__ b2,
                                            float* __restrict__ u,
                                            float* __restrict__ cout) {
    __shared__ float sm[D], sh[D], sv[D], red[256];
    int m = mention[0];
    int dm = min(deg[m], 255);
    int t = threadIdx.x;
    float a = 0.f;
    for (int j = 1; j <= dm; j++) a += h1m[(size_t)j * D + t];
    sm[t] = a / fmaxf((float)deg[m], 1.0f);
    sh[t] = h1m[t];
    __syncthreads();
    float acc = b2[t];
    for (int k = 0; k < D; k++)
        acc += sm[k] * W2l[(size_t)t * D + k] + sh[k] * W2r[(size_t)t * D + k];
    sv[t] = acc;
    red[t] = b2[t] * acc;
    __syncthreads();
    for (int o = 128; o; o >>= 1) {
        if (t < o) red[t] += red[t + o];
        __syncthreads();
    }
    if (t == 0) cout[0] = red[0];
    // u = [W2l^T v ; W2r^T v]
    float a1 = 0.f, a2 = 0.f;
    for (int n = 0; n < D; n++) {
        a1 += W2l[(size_t)n * D + t] * sv[n];
        a2 += W2r[(size_t)n * D + t] * sv[n];
    }
    u[t] = a1;
    u[D + t] = a2;
}

// ---------------- fused split-bf16 MFMA GEMM + relu + projection epilogue ----------------
// epilogue atomically accumulates s[row], t[row] (zeroed by memset before launch)
__global__ __launch_bounds__(256, 2)
void k_gemm_fused(const unsigned short* __restrict__ Ahi,
                  const unsigned short* __restrict__ Alo,
                  const unsigned short* __restrict__ Bhi,
                  const unsigned short* __restrict__ Blo,
                  const float* __restrict__ bias,
                  const float* __restrict__ u,    // u1[256] then u2[256]
                  float* __restrict__ s,
                  float* __restrict__ t_) {
    __shared__ unsigned short sA[2][BM * BK];
    __shared__ unsigned short sB[2][BN * BK];
    __shared__ float sred[BM], tred[BM];
    int tid = threadIdx.x;
    int br = blockIdx.x, bc = blockIdx.y;
    int lane = tid & 63, wv = tid >> 6;
    int wm = (wv >> 1) * 64, wn = (wv & 1) * 64;
    int q = lane >> 4, r = lane & 15;

    float biasv[4], u1v[4], u2v[4];
    #pragma unroll
    for (int nt = 0; nt < 4; nt++) {
        int gc = bc * BN + wn + nt * 16 + r;
        biasv[nt] = bias[gc];
        u1v[nt] = u[gc];
        u2v[nt] = u[256 + gc];
    }
    if (tid < BM) { sred[tid] = 0.f; tred[tid] = 0.f; }

    floatx4 acc[4][4] = {};

    const size_t arow0 = (size_t)br * BM;
    const int brow0 = bc * BN;
    int seg = lane & 3;
    int rl16 = lane >> 2;

    for (int kt = 0; kt < K2 / BK; kt++) {
        #pragma unroll
        for (int t = 0; t < 2; t++) {
            int rloc = wv * 32 + t * 16 + rl16;
            size_t gA = (arow0 + rloc) * (size_t)K2 + kt * BK + seg * 8;
            size_t gB = (size_t)(brow0 + rloc) * K2 + kt * BK + seg * 8;
            int ldsoff = (wv * 32 + t * 16) * BK;
            load_lds16(Ahi + gA, &sA[0][ldsoff]);
            load_lds16(Alo + gA, &sA[1][ldsoff]);
            load_lds16(Bhi + gB, &sB[0][ldsoff]);
            load_lds16(Blo + gB, &sB[1][ldsoff]);
        }
        __syncthreads();
        short8 ah[4], al[4], bh[4], bl[4];
        #pragma unroll
        for (int i = 0; i < 4; i++) {
            ah[i] = *(const short8*)&sA[0][(wm + i * 16 + r) * BK + q * 8];
            al[i] = *(const short8*)&sA[1][(wm + i * 16 + r) * BK + q * 8];
            bh[i] = *(const short8*)&sB[0][(wn + i * 16 + r) * BK + q * 8];
            bl[i] = *(const short8*)&sB[1][(wn + i * 16 + r) * BK + q * 8];
        }
        #pragma unroll
        for (int mt = 0; mt < 4; mt++)
            #pragma unroll
            for (int nt = 0; nt < 4; nt++) {
                acc[mt][nt] = __builtin_amdgcn_mfma_f32_16x16x32_bf16(ah[mt], bh[nt], acc[mt][nt], 0, 0, 0);
                acc[mt][nt] = __builtin_amdgcn_mfma_f32_16x16x32_bf16(ah[mt], bl[nt], acc[mt][nt], 0, 0, 0);
                acc[mt][nt] = __builtin_amdgcn_mfma_f32_16x16x32_bf16(al[mt], bh[nt], acc[mt][nt], 0, 0, 0);
            }
        __syncthreads();
    }

    #pragma unroll
    for (int mt = 0; mt < 4; mt++) {
        #pragma unroll
        for (int reg = 0; reg < 4; reg++) {
            float sacc = 0.f, tacc = 0.f;
            #pragma unroll
            for (int nt = 0; nt < 4; nt++) {
                float h = fmaxf(acc[mt][nt][reg] + biasv[nt], 0.f);
                sacc += h * u1v[nt];
                tacc += h * u2v[nt];
            }
            #pragma unroll
            for (int off = 1; off < 16; off <<= 1) {
                sacc += __shfl_xor(sacc, off);
                tacc += __shfl_xor(tacc, off);
            }
            if (r == 0) {
                int row = wm + mt * 16 + q * 4 + reg;
                atomicAdd(&sred[row], sacc);
                atomicAdd(&tred[row], tacc);
            }
        }
    }
    __syncthreads();
    if (tid < BM) {
        size_t grow = arow0 + tid;
        if (grow < N_NODES) {
            atomicAdd(&s[grow], sred[tid]);
            atomicAdd(&t_[grow], tred[tid]);
        }
    }
}

// ---------------- logits: gather s over CSR row + t + c ----------------
__global__ void k_logits(const int* __restrict__ deg, const int* __restrict__ cursor,
                         const int* __restrict__ csr,
                         const float* __restrict__ s, const float* __restrict__ t_,
                         const float* __restrict__ cptr, float* __restrict__ logits) {
    int i = blockIdx.x * blockDim.x + threadIdx.x;
    if (i >= N_NODES) return;
    int d = deg[i];
    int end = cursor[i];
    int start = end - d;
    float sum = 0.f;
    for (int j = start; j < end; j++) sum += s[csr[j]];
    logits[i] = sum / fmaxf((float)d, 1.0f) + t_[i] + cptr[0];
}

// ---------------- multi-block softmax ----------------
__global__ __launch_bounds__(1024) void k_sm1(const float* __restrict__ logits,
                                              float* __restrict__ pmax,
                                              float* __restrict__ psum) {
    __shared__ float red[1024];
    int b = blockIdx.x, t = threadIdx.x;
    int i = b * 1024 + t;
    float x = (i < N_NODES) ? logits[i] : -INFINITY;
    red[t] = x;
    __syncthreads();
    for (int o = 512; o; o >>= 1) {
        if (t < o) red[t] = fmaxf(red[t], red[t + o]);
        __syncthreads();
    }
    float mb = red[0];
    __syncthreads();
    red[t] = (i < N_NODES) ? __expf(x - mb) : 0.f;
    __syncthreads();
    for (int o = 512; o; o >>= 1) {
        if (t < o) red[t] += red[t + o];
        __syncthreads();
    }
    if (t == 0) { pmax[b] = mb; psum[b] = red[0]; }
}

__global__ void k_sm2(const float* __restrict__ pmax, const float* __restrict__ psum,
                      float* __restrict__ gS) {
    __shared__ float rm[64], rs[64];
    int t = threadIdx.x;
    float m = (t < SM_B) ? pmax[t] : -INFINITY;
    rm[t] = m;
    __syncthreads();
    for (int o = 32; o; o >>= 1) {
        if (t < o) rm[t] = fmaxf(rm[t], rm[t + o]);
        __syncthreads();
    }
    float g = rm[0];
    __syncthreads();
    rs[t] = (t < SM_B) ? psum[t] * __expf(m - g) : 0.f;
    __syncthreads();
    for (int o = 32; o; o >>= 1) {
        if (t < o) rs[t] += rs[t + o];
        __syncthreads();
    }
    if (t == 0) { gS[0] = g; gS[1] = 1.0f / rs[0]; }
}

__global__ void k_sm3(const float* __restrict__ logits, const float* __restrict__ gS,
                      float* __restrict__ out) {
    int i = blockIdx.x * blockDim.x + threadIdx.x;
    if (i < N_NODES) out[i] = __expf(logits[i] - gS[0]) * gS[1];
}

extern "C" void kernel_launch(void* const* d_in, const int* in_sizes, int n_in,
                              void* d_out, int out_size, void* d_ws, size_t ws_size,
                              hipStream_t stream) {
    const float* x   = (const float*)d_in[0];
    const int*   ei  = (const int*)d_in[1];
    const int*   src = ei;
    const int*   dst = ei + N_EDGES;
    const int*   mention = (const int*)d_in[2];
    const float* W1l = (const float*)d_in[3];
    const float* b1  = (const float*)d_in[4];
    const float* W1r = (const float*)d_in[5];
    const float* W2l = (const float*)d_in[6];
    const float* b2  = (const float*)d_in[7];
    const float* W2r = (const float*)d_in[8];

    char* w = (char*)d_ws;
    unsigned short* Ahi = (unsigned short*)w;  w += (size_t)M_PAD * K2 * 2;
    unsigned short* Alo = (unsigned short*)w;  w += (size_t)M_PAD * K2 * 2;
    unsigned short* Bhi = (unsigned short*)w;  w += (size_t)256 * K2 * 2;
    unsigned short* Blo = (unsigned short*)w;  w += (size_t)256 * K2 * 2;
    // zero region: s, t_, deg contiguous
    float* s     = (float*)w;  w += (size_t)N_NODES * 4;
    float* t_    = (float*)w;  w += (size_t)N_NODES * 4;
    int* deg     = (int*)w;    w += (size_t)N_NODES * 4;
    float* logit = (float*)w;  w += (size_t)N_NODES * 4;
    float* h1m   = (float*)w;  w += (size_t)256 * D * 4;
    float* u     = (float*)w;  w += 2 * D * 4;
    float* c     = (float*)w;  w += 16;
    float* pmax  = (float*)w;  w += 64 * 4;
    float* psum  = (float*)w;  w += 64 * 4;
    float* gS    = (float*)w;  w += 16;
    int* cursor  = (int*)w;    w += (size_t)N_NODES * 4;
    int* bsum    = (int*)w;    w += 256 * 4;
    int* boff    = (int*)w;    w += 256 * 4;
    int* csr     = (int*)w;    w += (size_t)N_EDGES * 4;

    hipMemsetAsync(s, 0, (size_t)3 * N_NODES * sizeof(float), stream);

    k_count <<<(N_EDGES + 255) / 256, 256, 0, stream>>>(dst, deg);
    k_scan1 <<<SCAN_B, 256, 0, stream>>>(deg, bsum);
    k_scan2 <<<1, 256, 0, stream>>>(bsum, boff);
    k_scan3 <<<SCAN_B, 256, 0, stream>>>(deg, boff, cursor);
    k_bucket<<<(N_EDGES + 255) / 256, 256, 0, stream>>>(src, dst, cursor, csr);

    k_splitX<<<(N_NODES * 64 + 255) / 256, 256, 0, stream>>>(x, Ahi, Alo);
    k_splitB<<<(256 * 128 + 255) / 256, 256, 0, stream>>>(W1l, W1r, Bhi, Blo);
    k_agg   <<<(N_NODES + 3) / 4, 256, 0, stream>>>(cursor, deg, csr, Ahi, Alo);

    k_small <<<256, 256, 0, stream>>>(mention, deg, cursor, csr, x, W1l, W1r, b1, h1m);
    k_vu    <<<1, 256, 0, stream>>>(mention, deg, h1m, W2l, W2r, b2, u, c);

    dim3 g1(M_PAD / BM, 2);
    k_gemm_fused<<<g1, 256, 0, stream>>>(Ahi, Alo, Bhi, Blo, b1, u, s, t_);

    k_logits<<<(N_NODES + 255) / 256, 256, 0, stream>>>(deg, cursor, csr, s, t_, c, logit);
    k_sm1   <<<SM_B, 1024, 0, stream>>>(logit, pmax, psum);
    k_sm2   <<<1, 64, 0, stream>>>(pmax, psum, gS);
    k_sm3   <<<(N_NODES + 255) / 256, 256, 0, stream>>>(logit, gS, (float*)d_out);
}

// Round 6
// 381.823 us; speedup vs baseline: 8.3444x; 1.0188x over previous
//
#include <hip/hip_runtime.h>
#include <math.h>

#define N_NODES 50000
#define N_EDGES 800000
#define D 256
#define K2 512        // concat [mean | x] feature dim
#define M_PAD 50048   // 391 * 128 rows (GEMM padding)
#define BM 128
#define BN 256
#define BK 32
#define SCAN_B 196    // ceil(N_NODES/256)

typedef __attribute__((ext_vector_type(8))) short short8;
typedef __attribute__((ext_vector_type(8))) unsigned short ushort8;
typedef __attribute__((ext_vector_type(4))) float floatx4;

__device__ __forceinline__ unsigned short bf16_rn(float f) {
    union { float f; unsigned u; } a; a.f = f;
    unsigned r = a.u + 0x7FFF + ((a.u >> 16) & 1);
    return (unsigned short)(r >> 16);
}
__device__ __forceinline__ float bf16_to_f(unsigned short h) {
    union { unsigned u; float f; } a; a.u = ((unsigned)h) << 16;
    return a.f;
}
__device__ __forceinline__ void load_lds16(const void* g, void* lds) {
    __builtin_amdgcn_global_load_lds((const __attribute__((address_space(1))) void*)g,
                                     (__attribute__((address_space(3))) void*)lds, 16, 0, 0);
}

// ---------------- CSR build ----------------
__global__ void k_count(const int* __restrict__ dst, int* __restrict__ deg) {
    int e = blockIdx.x * blockDim.x + threadIdx.x;
    if (e < N_EDGES) atomicAdd(&deg[dst[e]], 1);
}

__global__ void k_scan1(const int* __restrict__ deg, int* __restrict__ bsum) {
    __shared__ int red[256];
    int b = blockIdx.x, t = threadIdx.x;
    int i = b * 256 + t;
    red[t] = (i < N_NODES) ? deg[i] : 0;
    __syncthreads();
    for (int o = 128; o; o >>= 1) {
        if (t < o) red[t] += red[t + o];
        __syncthreads();
    }
    if (t == 0) bsum[b] = red[0];
}

__global__ void k_scan2(const int* __restrict__ bsum, int* __restrict__ boff) {
    __shared__ int sh[256];
    int t = threadIdx.x;
    sh[t] = (t < SCAN_B) ? bsum[t] : 0;
    __syncthreads();
    for (int o = 1; o < 256; o <<= 1) {
        int v = (t >= o) ? sh[t - o] : 0;
        __syncthreads();
        sh[t] += v;
        __syncthreads();
    }
    boff[t] = (t == 0) ? 0 : sh[t - 1];
}

__global__ void k_scan3(const int* __restrict__ deg, const int* __restrict__ boff,
                        int* __restrict__ cursor) {
    __shared__ int sh[256];
    int b = blockIdx.x, t = threadIdx.x;
    int i = b * 256 + t;
    int v = (i < N_NODES) ? deg[i] : 0;
    sh[t] = v;
    __syncthreads();
    for (int o = 1; o < 256; o <<= 1) {
        int val = (t >= o) ? sh[t - o] : 0;
        __syncthreads();
        sh[t] += val;
        __syncthreads();
    }
    if (i < N_NODES) cursor[i] = boff[b] + sh[t] - v;
}

// after this, cursor[i] == row END; start = cursor[i]-deg[i]
__global__ void k_bucket(const int* __restrict__ src, const int* __restrict__ dst,
                         int* __restrict__ cursor, int* __restrict__ csr_src) {
    int e = blockIdx.x * blockDim.x + threadIdx.x;
    if (e >= N_EDGES) return;
    int pos = atomicAdd(&cursor[dst[e]], 1);
    csr_src[pos] = src[e];
}

// ---------------- split x into bf16 hi/lo halves of A ----------------
__global__ void k_splitX(const float* __restrict__ x, unsigned short* __restrict__ Ahi,
                         unsigned short* __restrict__ Alo) {
    int t = blockIdx.x * blockDim.x + threadIdx.x;  // over N*64
    if (t >= N_NODES * 64) return;
    int m = t >> 6, j = (t & 63) * 4;
    float4 v = *(const float4*)&x[(size_t)m * D + j];
    ushort4 hi, lo;
    hi.x = bf16_rn(v.x); lo.x = bf16_rn(v.x - bf16_to_f(hi.x));
    hi.y = bf16_rn(v.y); lo.y = bf16_rn(v.y - bf16_to_f(hi.y));
    hi.z = bf16_rn(v.z); lo.z = bf16_rn(v.z - bf16_to_f(hi.z));
    hi.w = bf16_rn(v.w); lo.w = bf16_rn(v.w - bf16_to_f(hi.w));
    *(ushort4*)&Ahi[(size_t)m * K2 + 256 + j] = hi;
    *(ushort4*)&Alo[(size_t)m * K2 + 256 + j] = lo;
}

// ---------------- split [W1l|W1r] into bf16 hi/lo B ----------------
__global__ void k_splitB(const float* __restrict__ Wl, const float* __restrict__ Wr,
                         unsigned short* __restrict__ Bhi, unsigned short* __restrict__ Blo) {
    int t = blockIdx.x * blockDim.x + threadIdx.x;  // over 256*128
    if (t >= 256 * 128) return;
    int n = t >> 7, k = (t & 127) * 4;
    const float* srcp = (k < 256) ? &Wl[(size_t)n * 256 + k] : &Wr[(size_t)n * 256 + k - 256];
    float4 v = *(const float4*)srcp;
    ushort4 hi, lo;
    hi.x = bf16_rn(v.x); lo.x = bf16_rn(v.x - bf16_to_f(hi.x));
    hi.y = bf16_rn(v.y); lo.y = bf16_rn(v.y - bf16_to_f(hi.y));
    hi.z = bf16_rn(v.z); lo.z = bf16_rn(v.z - bf16_to_f(hi.z));
    hi.w = bf16_rn(v.w); lo.w = bf16_rn(v.w - bf16_to_f(hi.w));
    *(ushort4*)&Bhi[(size_t)n * K2 + k] = hi;
    *(ushort4*)&Blo[(size_t)n * K2 + k] = lo;
}

// ---------------- mean aggregation: 2 edges/wave, 16B/lane, unroll 4 ----------------
__global__ __launch_bounds__(256) void k_agg(const int* __restrict__ cursor,
                                             const int* __restrict__ deg,
                                             const int* __restrict__ csr,
                                             unsigned short* __restrict__ Ahi,
                                             unsigned short* __restrict__ Alo) {
    int node = blockIdx.x * 4 + (threadIdx.x >> 6);
    int lane = threadIdx.x & 63;
    if (node >= N_NODES) return;
    int d = deg[node], end = cursor[node], start = end - d;
    int h = lane >> 5;
    int col = (lane & 31) * 8;
    float acc0[8] = {}, acc1[8] = {};
    int j = start;
    for (; j + 4 <= end; j += 4) {
        int i0 = csr[j + h];
        int i1 = csr[j + 2 + h];
        ushort8 v0 = *(const ushort8*)&Ahi[(size_t)i0 * K2 + 256 + col];
        ushort8 v1 = *(const ushort8*)&Ahi[(size_t)i1 * K2 + 256 + col];
        #pragma unroll
        for (int k = 0; k < 8; k++) {
            acc0[k] += bf16_to_f(v0[k]);
            acc1[k] += bf16_to_f(v1[k]);
        }
    }
    if (j + 2 <= end) {
        int i0 = csr[j + h];
        ushort8 v0 = *(const ushort8*)&Ahi[(size_t)i0 * K2 + 256 + col];
        #pragma unroll
        for (int k = 0; k < 8; k++) acc0[k] += bf16_to_f(v0[k]);
        j += 2;
    }
    if (j < end && h == 0) {
        int i0 = csr[j];
        ushort8 v0 = *(const ushort8*)&Ahi[(size_t)i0 * K2 + 256 + col];
        #pragma unroll
        for (int k = 0; k < 8; k++) acc0[k] += bf16_to_f(v0[k]);
    }
    float inv = 1.0f / fmaxf((float)d, 1.0f);
    ushort8 hi, lo;
    #pragma unroll
    for (int k = 0; k < 8; k++) {
        float a = acc0[k] + acc1[k];
        a += __shfl_xor(a, 32);
        float m = a * inv;
        hi[k] = bf16_rn(m);
        lo[k] = bf16_rn(m - bf16_to_f(hi[k]));
    }
    if (h == 0) {
        *(ushort8*)&Ahi[(size_t)node * K2 + col] = hi;
        *(ushort8*)&Alo[(size_t)node * K2 + col] = lo;
    }
}

// ---------------- exact fp32 h1 rows for mention + its neighbors ----------------
__global__ __launch_bounds__(256) void k_small(const int* __restrict__ mention,
                                               const int* __restrict__ deg,
                                               const int* __restrict__ cursor,
                                               const int* __restrict__ csr,
                                               const float* __restrict__ x,
                                               const float* __restrict__ W1l,
                                               const float* __restrict__ W1r,
                                               const float* __restrict__ b1,
                                               float* __restrict__ h1m) {
    int m = mention[0];
    int dm = min(deg[m], 255);
    int slot = blockIdx.x;
    if (slot > dm) return;
    int startm = cursor[m] - deg[m];
    int node = (slot == 0) ? m : csr[startm + slot - 1];
    __shared__ float smean[D], sx[D];
    int t = threadIdx.x;
    int d = deg[node], end = cursor[node], start = end - d;
    float a = 0.f;
    for (int j = start; j < end; j++) a += x[(size_t)csr[j] * D + t];
    smean[t] = a / fmaxf((float)d, 1.0f);
    sx[t] = x[(size_t)node * D + t];
    __syncthreads();
    float z = b1[t];
    for (int k = 0; k < D; k++)
        z += smean[k] * W1l[(size_t)t * D + k] + sx[k] * W1r[(size_t)t * D + k];
    h1m[(size_t)slot * D + t] = fmaxf(z, 0.f);
}

// ---------------- v = h2[mention]; c = b2.v; u1 = W2l^T v; u2 = W2r^T v ----------------
__global__ __launch_bounds__(256) void k_vu(const int* __restrict__ mention,
                                            const int* __restrict__ deg,
                                            const float* __restrict__ h1m,
                                            const float* __restrict__ W2l,
                                            const float* __restrict__ W2r,
                                            const float* __restrict__ b2,
                                            float* __restrict__ u,
                                            float* __restrict__ cout) {
    __shared__ float sm[D], sh[D], sv[D], red[256];
    int m = mention[0];
    int dm = min(deg[m], 255);
    int t = threadIdx.x;
    float a = 0.f;
    for (int j = 1; j <= dm; j++) a += h1m[(size_t)j * D + t];
    sm[t] = a / fmaxf((float)deg[m], 1.0f);
    sh[t] = h1m[t];
    __syncthreads();
    float acc = b2[t];
    for (int k = 0; k < D; k++)
        acc += sm[k] * W2l[(size_t)t * D + k] + sh[k] * W2r[(size_t)t * D + k];
    sv[t] = acc;
    red[t] = b2[t] * acc;
    __syncthreads();
    for (int o = 128; o; o >>= 1) {
        if (t < o) red[t] += red[t + o];
        __syncthreads();
    }
    if (t == 0) cout[0] = red[0];
    float a1 = 0.f, a2 = 0.f;
    for (int n = 0; n < D; n++) {
        a1 += W2l[(size_t)n * D + t] * sv[n];
        a2 += W2r[(size_t)n * D + t] * sv[n];
    }
    u[t] = a1;
    u[D + t] = a2;
}

// ---------------- fused split-bf16 MFMA GEMM + relu + projection epilogue ----------------
// BM=128 x BN=256 (full width) per block, 512 threads / 8 waves of 64x64.
// A read exactly once; s,t stored directly (no atomics).
__global__ __launch_bounds__(512, 4)
void k_gemm_fused(const unsigned short* __restrict__ Ahi,
                  const unsigned short* __restrict__ Alo,
                  const unsigned short* __restrict__ Bhi,
                  const unsigned short* __restrict__ Blo,
                  const float* __restrict__ bias,
                  const float* __restrict__ u,    // u1[256] then u2[256]
                  float* __restrict__ s,
                  float* __restrict__ t_) {
    __shared__ unsigned short sA[2][BM * BK];   // 16 KB
    __shared__ unsigned short sB[2][BN * BK];   // 32 KB
    __shared__ float sred[BM], tred[BM];
    int tid = threadIdx.x;
    int br = blockIdx.x;
    int lane = tid & 63, wv = tid >> 6;          // 8 waves
    int wm = (wv >> 2) * 64, wn = (wv & 3) * 64; // 2x4 wave grid
    int q = lane >> 4, r = lane & 15;

    float biasv[4], u1v[4], u2v[4];
    #pragma unroll
    for (int nt = 0; nt < 4; nt++) {
        int gc = wn + nt * 16 + r;
        biasv[nt] = bias[gc];
        u1v[nt] = u[gc];
        u2v[nt] = u[256 + gc];
    }
    if (tid < BM) { sred[tid] = 0.f; tred[tid] = 0.f; }

    floatx4 acc[4][4] = {};

    const size_t arow0 = (size_t)br * BM;
    int seg = lane & 3;
    int rl16 = lane >> 2;

    for (int kt = 0; kt < K2 / BK; kt++) {
        {   // A: wave wv stages rows [wv*16, wv*16+16), hi+lo
            int rloc = wv * 16 + rl16;
            size_t gA = (arow0 + rloc) * (size_t)K2 + kt * BK + seg * 8;
            int ldsoff = (wv * 16) * BK;
            load_lds16(Ahi + gA, &sA[0][ldsoff]);
            load_lds16(Alo + gA, &sA[1][ldsoff]);
        }
        #pragma unroll
        for (int t = 0; t < 2; t++) {   // B: wave wv stages rows [wv*32, wv*32+32)
            int rloc = wv * 32 + t * 16 + rl16;
            size_t gB = (size_t)rloc * K2 + kt * BK + seg * 8;
            int ldsoff = (wv * 32 + t * 16) * BK;
            load_lds16(Bhi + gB, &sB[0][ldsoff]);
            load_lds16(Blo + gB, &sB[1][ldsoff]);
        }
        __syncthreads();
        short8 ah[4], al[4], bh[4], bl[4];
        #pragma unroll
        for (int i = 0; i < 4; i++) {
            ah[i] = *(const short8*)&sA[0][(wm + i * 16 + r) * BK + q * 8];
            al[i] = *(const short8*)&sA[1][(wm + i * 16 + r) * BK + q * 8];
            bh[i] = *(const short8*)&sB[0][(wn + i * 16 + r) * BK + q * 8];
            bl[i] = *(const short8*)&sB[1][(wn + i * 16 + r) * BK + q * 8];
        }
        #pragma unroll
        for (int mt = 0; mt < 4; mt++)
            #pragma unroll
            for (int nt = 0; nt < 4; nt++) {
                acc[mt][nt] = __builtin_amdgcn_mfma_f32_16x16x32_bf16(ah[mt], bh[nt], acc[mt][nt], 0, 0, 0);
                acc[mt][nt] = __builtin_amdgcn_mfma_f32_16x16x32_bf16(ah[mt], bl[nt], acc[mt][nt], 0, 0, 0);
                acc[mt][nt] = __builtin_amdgcn_mfma_f32_16x16x32_bf16(al[mt], bh[nt], acc[mt][nt], 0, 0, 0);
            }
        __syncthreads();
    }

    #pragma unroll
    for (int mt = 0; mt < 4; mt++) {
        #pragma unroll
        for (int reg = 0; reg < 4; reg++) {
            float sacc = 0.f, tacc = 0.f;
            #pragma unroll
            for (int nt = 0; nt < 4; nt++) {
                float h = fmaxf(acc[mt][nt][reg] + biasv[nt], 0.f);
                sacc += h * u1v[nt];
                tacc += h * u2v[nt];
            }
            #pragma unroll
            for (int off = 1; off < 16; off <<= 1) {
                sacc += __shfl_xor(sacc, off);
                tacc += __shfl_xor(tacc, off);
            }
            if (r == 0) {
                int row = wm + mt * 16 + q * 4 + reg;
                atomicAdd(&sred[row], sacc);
                atomicAdd(&tred[row], tacc);
            }
        }
    }
    __syncthreads();
    if (tid < BM) {
        size_t grow = arow0 + tid;
        if (grow < N_NODES) {
            s[grow] = sred[tid];
            t_[grow] = tred[tid];
        }
    }
}

// ---------------- fused logits + per-block softmax partials ----------------
__global__ __launch_bounds__(256) void k_logits_sm1(const int* __restrict__ deg,
                                                    const int* __restrict__ cursor,
                                                    const int* __restrict__ csr,
                                                    const float* __restrict__ s,
                                                    const float* __restrict__ t_,
                                                    const float* __restrict__ cptr,
                                                    float* __restrict__ logits,
                                                    float* __restrict__ pmax,
                                                    float* __restrict__ psum) {
    __shared__ float red[256];
    int b = blockIdx.x, t = threadIdx.x;
    int i = b * 256 + t;
    float lg = -INFINITY;
    if (i < N_NODES) {
        int d = deg[i];
        int end = cursor[i];
        int start = end - d;
        float sum = 0.f;
        for (int j = start; j < end; j++) sum += s[csr[j]];
        lg = sum / fmaxf((float)d, 1.0f) + t_[i] + cptr[0];
        logits[i] = lg;
    }
    red[t] = lg;
    __syncthreads();
    for (int o = 128; o; o >>= 1) {
        if (t < o) red[t] = fmaxf(red[t], red[t + o]);
        __syncthreads();
    }
    float mb = red[0];
    __syncthreads();
    red[t] = (i < N_NODES) ? __expf(lg - mb) : 0.f;
    __syncthreads();
    for (int o = 128; o; o >>= 1) {
        if (t < o) red[t] += red[t + o];
        __syncthreads();
    }
    if (t == 0) { pmax[b] = mb; psum[b] = red[0]; }
}

// combine 196 partials
__global__ void k_sm2(const float* __restrict__ pmax, const float* __restrict__ psum,
                      float* __restrict__ gS) {
    __shared__ float rm[256], rs[256];
    int t = threadIdx.x;
    float m = (t < SCAN_B) ? pmax[t] : -INFINITY;
    rm[t] = m;
    __syncthreads();
    for (int o = 128; o; o >>= 1) {
        if (t < o) rm[t] = fmaxf(rm[t], rm[t + o]);
        __syncthreads();
    }
    float g = rm[0];
    __syncthreads();
    rs[t] = (t < SCAN_B) ? psum[t] * __expf(m - g) : 0.f;
    __syncthreads();
    for (int o = 128; o; o >>= 1) {
        if (t < o) rs[t] += rs[t + o];
        __syncthreads();
    }
    if (t == 0) { gS[0] = g; gS[1] = 1.0f / rs[0]; }
}

__global__ void k_sm3(const float* __restrict__ logits, const float* __restrict__ gS,
                      float* __restrict__ out) {
    int i = blockIdx.x * blockDim.x + threadIdx.x;
    if (i < N_NODES) out[i] = __expf(logits[i] - gS[0]) * gS[1];
}

extern "C" void kernel_launch(void* const* d_in, const int* in_sizes, int n_in,
                              void* d_out, int out_size, void* d_ws, size_t ws_size,
                              hipStream_t stream) {
    const float* x   = (const float*)d_in[0];
    const int*   ei  = (const int*)d_in[1];
    const int*   src = ei;
    const int*   dst = ei + N_EDGES;
    const int*   mention = (const int*)d_in[2];
    const float* W1l = (const float*)d_in[3];
    const float* b1  = (const float*)d_in[4];
    const float* W1r = (const float*)d_in[5];
    const float* W2l = (const float*)d_in[6];
    const float* b2  = (const float*)d_in[7];
    const float* W2r = (const float*)d_in[8];

    char* w = (char*)d_ws;
    unsigned short* Ahi = (unsigned short*)w;  w += (size_t)M_PAD * K2 * 2;
    unsigned short* Alo = (unsigned short*)w;  w += (size_t)M_PAD * K2 * 2;
    unsigned short* Bhi = (unsigned short*)w;  w += (size_t)256 * K2 * 2;
    unsigned short* Blo = (unsigned short*)w;  w += (size_t)256 * K2 * 2;
    float* s     = (float*)w;  w += (size_t)N_NODES * 4;
    float* t_    = (float*)w;  w += (size_t)N_NODES * 4;
    int* deg     = (int*)w;    w += (size_t)N_NODES * 4;   // zeroed
    float* logit = (float*)w;  w += (size_t)N_NODES * 4;
    float* h1m   = (float*)w;  w += (size_t)256 * D * 4;
    float* u     = (float*)w;  w += 2 * D * 4;
    float* c     = (float*)w;  w += 16;
    float* pmax  = (float*)w;  w += 256 * 4;
    float* psum  = (float*)w;  w += 256 * 4;
    float* gS    = (float*)w;  w += 16;
    int* cursor  = (int*)w;    w += (size_t)N_NODES * 4;
    int* bsum    = (int*)w;    w += 256 * 4;
    int* boff    = (int*)w;    w += 256 * 4;
    int* csr     = (int*)w;    w += (size_t)N_EDGES * 4;

    hipMemsetAsync(deg, 0, (size_t)N_NODES * sizeof(int), stream);

    k_count <<<(N_EDGES + 255) / 256, 256, 0, stream>>>(dst, deg);
    k_scan1 <<<SCAN_B, 256, 0, stream>>>(deg, bsum);
    k_scan2 <<<1, 256, 0, stream>>>(bsum, boff);
    k_scan3 <<<SCAN_B, 256, 0, stream>>>(deg, boff, cursor);
    k_bucket<<<(N_EDGES + 255) / 256, 256, 0, stream>>>(src, dst, cursor, csr);

    k_splitX<<<(N_NODES * 64 + 255) / 256, 256, 0, stream>>>(x, Ahi, Alo);
    k_splitB<<<(256 * 128 + 255) / 256, 256, 0, stream>>>(W1l, W1r, Bhi, Blo);
    k_agg   <<<(N_NODES + 3) / 4, 256, 0, stream>>>(cursor, deg, csr, Ahi, Alo);

    k_small <<<256, 256, 0, stream>>>(mention, deg, cursor, csr, x, W1l, W1r, b1, h1m);
    k_vu    <<<1, 256, 0, stream>>>(mention, deg, h1m, W2l, W2r, b2, u, c);

    k_gemm_fused<<<M_PAD / BM, 512, 0, stream>>>(Ahi, Alo, Bhi, Blo, b1, u, s, t_);

    k_logits_sm1<<<SCAN_B, 256, 0, stream>>>(deg, cursor, csr, s, t_, c, logit, pmax, psum);
    k_sm2   <<<1, 256, 0, stream>>>(pmax, psum, gS);
    k_sm3   <<<(N_NODES + 255) / 256, 256, 0, stream>>>(logit, gS, (float*)d_out);
}